// Round 12
// baseline (990.903 us; speedup 1.0000x reference)
//
#include <hip/hip_runtime.h>
#include <hip/hip_cooperative_groups.h>

namespace cg = cooperative_groups;

static inline int ceil_div(int a, int b) { return (a + b - 1) / b; }

typedef __attribute__((ext_vector_type(8))) short short8;
typedef __attribute__((ext_vector_type(4))) float floatx4;

__device__ __forceinline__ unsigned short f2bf(float f) {
    unsigned int u = __float_as_uint(f);
    unsigned int r = (u + 0x7fffu + ((u >> 16) & 1u)) >> 16;
    return (unsigned short)r;
}
__device__ __forceinline__ float bf2f(unsigned short h) {
    return __uint_as_float(((unsigned int)h) << 16);
}

// ---------------- CSR scan ----------------
__global__ __launch_bounds__(1024) void scan1_k(const int* __restrict__ deg,
                                                int* __restrict__ excl,
                                                int* __restrict__ bsum, int Nv) {
    __shared__ int s[1024];
    int tid = threadIdx.x;
    int i = blockIdx.x * 1024 + tid;
    int v = (i < Nv) ? deg[i] : 0;
    s[tid] = v;
    __syncthreads();
    for (int off = 1; off < 1024; off <<= 1) {
        int t = (tid >= off) ? s[tid - off] : 0;
        __syncthreads();
        if (tid >= off) s[tid] += t;
        __syncthreads();
    }
    if (i < Nv) excl[i] = s[tid] - v;
    if (tid == 1023) bsum[blockIdx.x] = s[1023];
}

// scan3 with inline block-offset prefix (nb <= 64)
__global__ __launch_bounds__(1024) void scan3_k(const int* __restrict__ excl,
                                                const int* __restrict__ bsum,
                                                const int* __restrict__ deg,
                                                int* __restrict__ rowptr,
                                                int* __restrict__ cursor, int Nv, int nb) {
    __shared__ int offS;
    if (threadIdx.x < 64) {
        int v = (threadIdx.x < min((int)blockIdx.x, nb)) ? bsum[threadIdx.x] : 0;
#pragma unroll
        for (int m = 1; m < 64; m <<= 1) v += __shfl_xor(v, m);
        if (threadIdx.x == 0) offS = v;
    }
    __syncthreads();
    int i = blockIdx.x * 1024 + threadIdx.x;
    if (i < Nv) {
        int val = excl[i] + offS;
        rowptr[i] = val;
        cursor[i] = val;
        if (i == Nv - 1) rowptr[Nv] = val + deg[i];
    }
}

__global__ __launch_bounds__(256) void fill_adj_k(const int* __restrict__ edges,
                                                  int* __restrict__ cursor,
                                                  int* __restrict__ adj, int E) {
    int e = blockIdx.x * blockDim.x + threadIdx.x;
    if (e < E) {
        int a = edges[2 * e], b = edges[2 * e + 1];
        adj[atomicAdd(&cursor[a], 1)] = b;
        adj[atomicAdd(&cursor[b], 1)] = a;
    }
}

// ---------------- fat prologue: count_deg | prep_w | prep_bwT | enc_proj | fm transpose ----
__global__ __launch_bounds__(256) void fatpre_k(
    const int* __restrict__ edges, int* __restrict__ deg, int E, int nE,
    const float* __restrict__ g0w0, const float* __restrict__ g0w1,
    const float* __restrict__ gw0, const float* __restrict__ gw1,
    unsigned short* __restrict__ Wt, const float* __restrict__ bw,
    unsigned short* __restrict__ bwT, const float* __restrict__ enc,
    float* __restrict__ encp, const float* __restrict__ fm1, const float* __restrict__ fm2,
    const float* __restrict__ fm3, const float* __restrict__ fm4,
    unsigned short* __restrict__ ft1, unsigned short* __restrict__ ft2,
    unsigned short* __restrict__ ft3, unsigned short* __restrict__ ft4, int B_) {
    __shared__ float tl[64][65];  // transpose staging (role 5 only)
    int bid = blockIdx.x;
    int tid = threadIdx.x;
    if (bid < nE) {
        int e = bid * 256 + tid;
        if (e < E) {
            atomicAdd(&deg[edges[2 * e]], 1);
            atomicAdd(&deg[edges[2 * e + 1]], 1);
        }
    } else if (bid < nE + 16) {
        int lh = bid - nE;
        int l = lh >> 1, h = lh & 1;
        const float* src;
        if (l == 0) src = h ? g0w1 : g0w0;
        else src = (h ? gw1 : gw0) + (size_t)(l - 1) * 16384;
        unsigned short* dst = Wt + (size_t)lh * 16384;
        for (int idx = tid; idx < 16384; idx += 256) {
            int n = idx >> 7, k = idx & 127;
            dst[n * 128 + k] = f2bf(src[k * 128 + n]);
        }
    } else if (bid < nE + 46) {
        // bottleneck weight transpose+cast: bwT[n][k] = bf16(bw[k][n])
        int blk = bid - nE - 16;  // 0..29
        for (int idx = tid; idx < 16384; idx += 256) {
            int n = idx >> 7, kk = idx & 127;
            bwT[(size_t)n * 3840 + blk * 128 + kk] =
                f2bf(bw[(size_t)(blk * 128 + kk) * 128 + n]);
        }
    } else if (bid < nE + 46 + B_) {
        int b = bid - nE - 46;
        int sH = tid >> 7;
        int j = tid & 127;
        const float* w = sH ? g0w1 : g0w0;
        const float* eb = enc + b * 256;
        float acc = 0.f;
        for (int c = 0; c < 256; ++c) acc = fmaf(eb[c], w[(131 + c) * 128 + j], acc);
        encp[(sH * B_ + b) * 128 + j] = acc;
    } else {
        // feature-map transpose role
        int idx = bid - (nE + 46 + B_);
        const float* fm;
        unsigned short* ft;
        int C, HW, PT, CT;
        int q1 = 49 * 4 * B_, q2 = 13 * 8 * B_, q3 = 4 * 16 * B_;
        if (idx < q1) {
            fm = fm1; ft = ft1; C = 256; HW = 3136; PT = 49; CT = 4;
        } else if ((idx -= q1) < q2) {
            fm = fm2; ft = ft2; C = 512; HW = 784; PT = 13; CT = 8;
        } else if ((idx -= q2) < q3) {
            fm = fm3; ft = ft3; C = 1024; HW = 196; PT = 4; CT = 16;
        } else {
            idx -= q3;
            fm = fm4; ft = ft4; C = 2048; HW = 49; PT = 1; CT = 32;
        }
        int ct = idx % CT;
        int r2 = idx / CT;
        int pt = r2 % PT;
        int b = r2 / PT;
        int p0 = pt * 64, c0 = ct * 64;
        const float* fb = fm + (size_t)b * C * HW;
#pragma unroll
        for (int l = 0; l < 4; ++l) {
            int i = tid + l * 256;  // 0..1023
            int ch = i >> 4;
            int pq = (i & 15) * 4;
            const float* src = fb + (size_t)(c0 + ch) * HW + p0 + pq;
            float4 v;
            if (p0 + pq + 3 < HW) {
                v = *(const float4*)src;
            } else {
                v.x = (p0 + pq + 0 < HW) ? src[0] : 0.f;
                v.y = (p0 + pq + 1 < HW) ? src[1] : 0.f;
                v.z = (p0 + pq + 2 < HW) ? src[2] : 0.f;
                v.w = (p0 + pq + 3 < HW) ? src[3] : 0.f;
            }
            tl[ch][pq + 0] = v.x;
            tl[ch][pq + 1] = v.y;
            tl[ch][pq + 2] = v.z;
            tl[ch][pq + 3] = v.w;
        }
        __syncthreads();
#pragma unroll
        for (int l = 0; l < 2; ++l) {
            int i = tid + l * 256;  // 0..511
            int p = i >> 3;
            int cc = (i & 7) * 8;
            if (p0 + p < HW) {
                short8 o;
#pragma unroll
                for (int j = 0; j < 8; ++j) o[j] = (short)f2bf(tl[cc + j][p]);
                *(short8*)(ft + ((size_t)b * HW + p0 + p) * C + c0 + cc) = o;
            }
        }
    }
}

// ---------------- pixel projection via MFMA (K up to 256/block, direct bf16 A-loads) --
__global__ __launch_bounds__(256) void proj_all_k(
    const unsigned short* __restrict__ ft1, const unsigned short* __restrict__ ft2,
    const unsigned short* __restrict__ ft3, const unsigned short* __restrict__ ft4,
    const unsigned short* __restrict__ bwT, float* __restrict__ o1, float* __restrict__ o2,
    float* __restrict__ o3, float* __restrict__ o4, int B_) {
    __shared__ unsigned short wlds[8192];  // 16 KB: [128 n][64 k] bf16, XOR-swizzled

    int tid = threadIdx.x;
    // blocks per level: PT * B * (C / KB); KB = 128 (lvl1) or 256 (lvls 2-4)
    int n1 = 49 * B_ * 2, n2 = 13 * B_ * 2, n3 = 4 * B_ * 4;
    int bid = blockIdx.x;
    const unsigned short* ft;
    float* op;
    int C, HW, PT, idx, koff, KB;
    if (bid < n1) {
        ft = ft1; op = o1; C = 256; HW = 3136; PT = 49; idx = bid; koff = 0; KB = 128;
    } else if (bid < n1 + n2) {
        ft = ft2; op = o2; C = 512; HW = 784; PT = 13; idx = bid - n1; koff = 256; KB = 256;
    } else if (bid < n1 + n2 + n3) {
        ft = ft3; op = o3; C = 1024; HW = 196; PT = 4; idx = bid - n1 - n2; koff = 768;
        KB = 256;
    } else {
        ft = ft4; op = o4; C = 2048; HW = 49; PT = 1; idx = bid - n1 - n2 - n3; koff = 1792;
        KB = 256;
    }
    int pt = idx % PT;
    int r2 = idx / PT;
    int b = r2 % B_;
    int zz = r2 / B_;
    int p0 = pt * 64;
    int kcf0 = zz * KB;  // this block's KB-wide channel window

    int wave = tid >> 6, lane = tid & 63;
    int row16 = lane & 15, quad = lane >> 4;
    int p = p0 + wave * 16 + row16;
    bool pok = (p < HW);
    int pc = pok ? p : (HW - 1);
    const unsigned short* frow = ft + ((size_t)b * HW + pc) * C;

    floatx4 acc[8];
#pragma unroll
    for (int j = 0; j < 8; ++j) acc[j] = (floatx4){0.f, 0.f, 0.f, 0.f};

    int nzz = KB >> 6;
    for (int zz2 = 0; zz2 < nzz; ++zz2) {
        int kcf = kcf0 + zz2 * 64;
        int kcw = koff + kcf;
        if (zz2) __syncthreads();  // protect previous chunk's wlds reads
        // stage W^T tile [128 n][64 k] bf16, swizzled
#pragma unroll
        for (int l = 0; l < 4; ++l) {
            int i2 = tid + l * 256;  // 0..1023
            int n = i2 >> 3, c16 = i2 & 7;
            *(short8*)&wlds[n * 64 + ((c16 ^ (n & 7)) * 8)] =
                *(const short8*)(bwT + (size_t)n * 3840 + kcw + c16 * 8);
        }
        // A-fragments: 2 direct 16B loads (K-contiguous bf16 rows)
        short8 ax[2];
#pragma unroll
        for (int ks = 0; ks < 2; ++ks)
            ax[ks] = *(const short8*)(frow + kcf + ks * 32 + quad * 8);
        __syncthreads();
#pragma unroll
        for (int ks = 0; ks < 2; ++ks) {
            int c = ks * 4 + quad;
#pragma unroll
            for (int nt = 0; nt < 8; ++nt) {
                int wr = nt * 16 + row16;
                short8 bwf = *(short8*)&wlds[wr * 64 + ((c ^ (wr & 7)) * 8)];
                acc[nt] =
                    __builtin_amdgcn_mfma_f32_16x16x32_bf16(ax[ks], bwf, acc[nt], 0, 0, 0);
            }
        }
    }

    float* obase = op + (size_t)b * HW * 128;
#pragma unroll
    for (int nt = 0; nt < 8; ++nt) {
        int colg = nt * 16 + row16;
#pragma unroll
        for (int rr = 0; rr < 4; ++rr) {
            int pr = p0 + wave * 16 + quad * 4 + rr;
            if (pr < HW) atomicAdd(&obase[(size_t)pr * 128 + colg], acc[nt][rr]);
        }
    }
}

// ---------------- bilinear sample + bottleneck relu + layer0 pre terms (wave/vertex) ---
__device__ __forceinline__ void sample2(const float* __restrict__ pp, int Hh, int Ww,
                                        float gx, float gy, int c2, float& a0, float& a1) {
    float x = (gx + 1.f) * 0.5f * (float)(Ww - 1);
    float y = (gy + 1.f) * 0.5f * (float)(Hh - 1);
    float x0f = floorf(x), y0f = floorf(y);
    float wx1 = x - x0f, wy1 = y - y0f;
    float wx0 = 1.f - wx1, wy0 = 1.f - wy1;
    int x0 = (int)fminf(fmaxf(x0f, 0.f), (float)(Ww - 1));
    int x1 = (int)fminf(fmaxf(x0f + 1.f, 0.f), (float)(Ww - 1));
    int y0 = (int)fminf(fmaxf(y0f, 0.f), (float)(Hh - 1));
    int y1 = (int)fminf(fmaxf(y0f + 1.f, 0.f), (float)(Hh - 1));
    float2 r00 = *(const float2*)(pp + (size_t)(y0 * Ww + x0) * 128 + c2);
    float2 r01 = *(const float2*)(pp + (size_t)(y0 * Ww + x1) * 128 + c2);
    float2 r10 = *(const float2*)(pp + (size_t)(y1 * Ww + x0) * 128 + c2);
    float2 r11 = *(const float2*)(pp + (size_t)(y1 * Ww + x1) * 128 + c2);
    a0 += wy0 * (wx0 * r00.x + wx1 * r01.x) + wy1 * (wx0 * r10.x + wx1 * r11.x);
    a1 += wy0 * (wx0 * r00.y + wx1 * r01.y) + wy1 * (wx0 * r10.y + wx1 * r11.y);
}

__global__ __launch_bounds__(256) void sample_bottleneck_k(
    const float* __restrict__ av, const float* __restrict__ pp1, const float* __restrict__ pp2,
    const float* __restrict__ pp3, const float* __restrict__ pp4, const float* __restrict__ bb,
    const float* __restrict__ verts, const float* __restrict__ encp,
    const float* __restrict__ g0w0, const float* __restrict__ g0w1,
    const float* __restrict__ g0b0, const float* __restrict__ g0b1,
    unsigned short* __restrict__ X, unsigned short* __restrict__ H, int Nv, int V_, int B_) {
    int wave = threadIdx.x >> 6, lane = threadIdx.x & 63;
    int n = blockIdx.x * 4 + wave;
    if (n >= Nv) return;
    int b = n / V_;
    int c2 = 2 * lane;
    float gx = av[(size_t)n * 3 + 0];
    float gy = av[(size_t)n * 3 + 1];
    float2 bbv = *(const float2*)(bb + c2);
    float a0 = bbv.x, a1 = bbv.y;
    sample2(pp1 + (size_t)b * 3136 * 128, 56, 56, gx, gy, c2, a0, a1);
    sample2(pp2 + (size_t)b * 784 * 128, 28, 28, gx, gy, c2, a0, a1);
    sample2(pp3 + (size_t)b * 196 * 128, 14, 14, gx, gy, c2, a0, a1);
    sample2(pp4 + (size_t)b * 49 * 128, 7, 7, gx, gy, c2, a0, a1);
    *(unsigned int*)(X + (size_t)n * 128 + c2) =
        (unsigned int)f2bf(fmaxf(a0, 0.f)) | ((unsigned int)f2bf(fmaxf(a1, 0.f)) << 16);

    float v0 = verts[n * 3 + 0], v1 = verts[n * 3 + 1], v2 = verts[n * 3 + 2];
    float2 e0 = *(const float2*)(encp + ((size_t)(0 * B_ + b)) * 128 + c2);
    float2 e1 = *(const float2*)(encp + ((size_t)(1 * B_ + b)) * 128 + c2);
    float2 gb0v = *(const float2*)(g0b0 + c2);
    float2 gb1v = *(const float2*)(g0b1 + c2);
    float2 w0a = *(const float2*)(g0w0 + 128 * 128 + c2);
    float2 w0b = *(const float2*)(g0w0 + 129 * 128 + c2);
    float2 w0c = *(const float2*)(g0w0 + 130 * 128 + c2);
    float2 w1a = *(const float2*)(g0w1 + 128 * 128 + c2);
    float2 w1b = *(const float2*)(g0w1 + 129 * 128 + c2);
    float2 w1c = *(const float2*)(g0w1 + 130 * 128 + c2);
    float h0x = e0.x + gb0v.x + v0 * w0a.x + v1 * w0b.x + v2 * w0c.x;
    float h0y = e0.y + gb0v.y + v0 * w0a.y + v1 * w0b.y + v2 * w0c.y;
    float h1x = e1.x + gb1v.x + v0 * w1a.x + v1 * w1b.x + v2 * w1c.x;
    float h1y = e1.y + gb1v.y + v0 * w1a.y + v1 * w1b.y + v2 * w1c.y;
    *(unsigned int*)(H + (size_t)n * 256 + c2) =
        (unsigned int)f2bf(h0x) | ((unsigned int)f2bf(h0y) << 16);
    *(unsigned int*)(H + (size_t)n * 256 + 128 + c2) =
        (unsigned int)f2bf(h1x) | ((unsigned int)f2bf(h1y) << 16);
}

// ---------------- layer-0 gather v2: 4 vertices/wave, AggX=sum X, AggH=h0+sum h1 -------
__global__ __launch_bounds__(256) void agg0_k(const unsigned short* __restrict__ X,
                                              const unsigned short* __restrict__ H,
                                              const int* __restrict__ rowptr,
                                              const int* __restrict__ adj,
                                              unsigned short* __restrict__ AggX,
                                              unsigned short* __restrict__ AggH, int Nv,
                                              int Etot) {
    int wave = threadIdx.x >> 6, lane = threadIdx.x & 63;
    int n0 = (blockIdx.x * 4 + wave) * 4;
    if (n0 >= Nv) return;
    int g = lane >> 4, c = lane & 15;
    int rp = rowptr[min(n0 + (lane & 7), Nv)];
    int sg = __shfl(rp, g);
    int eg = __shfl(rp, g + 1);
    int m = eg - sg;
    m = max(m, __shfl_xor(m, 16));
    m = max(m, __shfl_xor(m, 32));

    int n = n0 + g;
    bool nok = (n < Nv);
    int nc = nok ? n : (Nv - 1);
    float accx[8], acch[8];
    short8 h0v = *(const short8*)(H + (size_t)nc * 256 + c * 8);
#pragma unroll
    for (int j = 0; j < 8; ++j) {
        accx[j] = 0.f;
        acch[j] = bf2f((unsigned short)h0v[j]);
    }

    for (int it = 0; it < m; it += 8) {
        int t = sg + it + (lane & 7);
        int adjv = adj[min(t, Etot - 1)];
        short8 bx[8], bh[8];
#pragma unroll
        for (int q = 0; q < 8; ++q) {
            int nbq = __shfl(adjv, (lane & 48) + q);
            bx[q] = *(const short8*)(X + (size_t)nbq * 128 + c * 8);
            bh[q] = *(const short8*)(H + (size_t)nbq * 256 + 128 + c * 8);
        }
#pragma unroll
        for (int q = 0; q < 8; ++q) {
            bool ok = (sg + it + q < eg);
#pragma unroll
            for (int j = 0; j < 8; ++j) {
                accx[j] += ok ? bf2f((unsigned short)bx[q][j]) : 0.f;
                acch[j] += ok ? bf2f((unsigned short)bh[q][j]) : 0.f;
            }
        }
    }
    if (nok) {
        short8 ox, oh;
#pragma unroll
        for (int j = 0; j < 8; ++j) {
            ox[j] = (short)f2bf(accx[j]);
            oh[j] = (short)f2bf(acch[j]);
        }
        *(short8*)(AggX + (size_t)n * 128 + c * 8) = ox;
        *(short8*)(AggH + (size_t)n * 128 + c * 8) = oh;
    }
}

// ---------------- dual-MFMA layer GEMM (layer 0 only): 128-row x 64-col tiles ---------
__global__ __launch_bounds__(256, 3) void gemm_dual_k(
    const unsigned short* __restrict__ Xin, const unsigned short* __restrict__ Agg,
    const unsigned short* __restrict__ Wt,  // [2][128][128] bf16 n-major (W0, W1)
    const float* __restrict__ b0, const float* __restrict__ b1,
    const unsigned short* __restrict__ aggh, const int* __restrict__ degv,
    unsigned short* __restrict__ Xout, int M) {
    __shared__ unsigned short wlds[16384];  // 32 KB weights (stays live both sub-tiles)
    __shared__ unsigned short cs[64 * 72];  // 9 KB epilogue staging
    __shared__ float bS[128];

    int tid = threadIdx.x;
    int m0 = blockIdx.x * 128;
    int yb = blockIdx.y;

    int wave = tid >> 6, lane = tid & 63;
    int row16 = lane & 15;
    int quad = lane >> 4;
    int wrow = wave * 16;

    short8 axT[2][4], agT[2][4];
    int dgT[2][4];
    {
        int g = min(m0 + wrow + row16, M - 1);
#pragma unroll
        for (int ks = 0; ks < 4; ++ks) {
            int koff = ks * 32 + quad * 8;
            axT[0][ks] = *(const short8*)(Xin + (size_t)g * 128 + koff);
            agT[0][ks] = *(const short8*)(Agg + (size_t)g * 128 + koff);
        }
#pragma unroll
        for (int rr = 0; rr < 4; ++rr)
            dgT[0][rr] = degv[min(m0 + wrow + quad * 4 + rr, M - 1)];
    }

    if (tid < 64) {
        bS[tid] = b0 ? b0[yb * 64 + tid] : 0.f;
        bS[64 + tid] = b1 ? b1[yb * 64 + tid] : 0.f;
    }

    const unsigned short* W0h = Wt + (size_t)yb * 64 * 128;
    const unsigned short* W1h = Wt + 16384 + (size_t)yb * 64 * 128;
#pragma unroll
    for (int l = 0; l < 8; ++l) {
        int idx = tid + l * 256;      // 0..2047 16B chunks
        int half = idx >> 10;
        int r = (idx >> 4) & 63;
        int c16 = idx & 15;
        int sw = (c16 ^ (r & 15)) * 8;
        const unsigned short* src = (half ? W1h : W0h) + r * 128 + c16 * 8;
        *(short8*)&wlds[half * 8192 + r * 128 + sw] = *(const short8*)src;
    }
    __syncthreads();

    {
        int g = min(m0 + 64 + wrow + row16, M - 1);
#pragma unroll
        for (int ks = 0; ks < 4; ++ks) {
            int koff = ks * 32 + quad * 8;
            axT[1][ks] = *(const short8*)(Xin + (size_t)g * 128 + koff);
            agT[1][ks] = *(const short8*)(Agg + (size_t)g * 128 + koff);
        }
#pragma unroll
        for (int rr = 0; rr < 4; ++rr)
            dgT[1][rr] = degv[min(m0 + 64 + wrow + quad * 4 + rr, M - 1)];
    }

#pragma unroll
    for (int t = 0; t < 2; ++t) {
        int mT = m0 + t * 64;
        floatx4 acc[4];
#pragma unroll
        for (int j = 0; j < 4; j++) acc[j] = (floatx4){0.f, 0.f, 0.f, 0.f};

#pragma unroll
        for (int ks = 0; ks < 4; ++ks) {
            int c = ks * 4 + quad;
#pragma unroll
            for (int nt = 0; nt < 4; ++nt) {
                int wr = nt * 16 + row16;
                short8 bw0 = *(short8*)&wlds[wr * 128 + ((c ^ row16) * 8)];
                short8 bw1 = *(short8*)&wlds[8192 + wr * 128 + ((c ^ row16) * 8)];
                acc[nt] = __builtin_amdgcn_mfma_f32_16x16x32_bf16(axT[t][ks], bw0, acc[nt], 0, 0, 0);
                acc[nt] = __builtin_amdgcn_mfma_f32_16x16x32_bf16(agT[t][ks], bw1, acc[nt], 0, 0, 0);
            }
        }

#pragma unroll
        for (int nt = 0; nt < 4; ++nt) {
            int colh = nt * 16 + row16;
            int colg = yb * 64 + colh;
            float bc0 = bS[colh];
            float bc1 = bS[64 + colh];
#pragma unroll
            for (int rr = 0; rr < 4; ++rr) {
                int row = wrow + quad * 4 + rr;
                int gm = mT + row;
                float v = acc[nt][rr] + bc0 + (float)dgT[t][rr] * bc1;
                if (aggh && gm < M) v += bf2f(aggh[(size_t)gm * 128 + colg]);
                cs[row * 72 + colh] = f2bf(fmaxf(v, 0.f));
            }
        }
        __syncthreads();

        {
            int r = tid >> 2;
            int cq = (tid & 3) * 16;
            int gm = mT + r;
            if (gm < M) {
                unsigned short* dst = Xout + (size_t)gm * 128 + yb * 64 + cq;
                *(short8*)dst = *(short8*)&cs[r * 72 + cq];
                *(short8*)(dst + 8) = *(short8*)&cs[r * 72 + cq + 8];
            }
        }
        __syncthreads();
    }
}

// ---------------- cooperative persistent layers 1..7: gather phase | GEMM phase -------
// Replaces 14 dispatch boundaries with grid syncs. Both phase bodies are
// byte-identical to the proven dedicated kernels (v2 gather / gemm_dual).
__global__ __launch_bounds__(256, 3) void layers_coop_k(
    unsigned short* __restrict__ X0, unsigned short* __restrict__ X1,
    const int* __restrict__ rowptr, const int* __restrict__ adj,
    const unsigned short* __restrict__ Wtb, const float* __restrict__ gb0,
    const float* __restrict__ gb1, unsigned short* __restrict__ Agg,
    const int* __restrict__ degv, int M, int Etot, const float* __restrict__ ow,
    const float* __restrict__ ob, float* __restrict__ outp) {
    cg::grid_group gridg = cg::this_grid();
    __shared__ unsigned short wlds[16384];
    __shared__ unsigned short cs[64 * 72];
    __shared__ float bS[128];
    __shared__ float owS[192];

    int tid = threadIdx.x;
    int wave = tid >> 6, lane = tid & 63;
    int row16 = lane & 15, quad = lane >> 4;
    int wrow = wave * 16;
    int nchunks = (M + 15) >> 4;
    int ntiles = ((M + 127) >> 7) * 2;

    for (int layer = 0; layer < 7; ++layer) {
        const unsigned short* Xin = (layer & 1) ? X1 : X0;
        unsigned short* Xout = (layer & 1) ? X0 : X1;
        const unsigned short* Wt = Wtb + (size_t)(layer + 1) * 32768;
        const float* b0 = gb0 + layer * 128;
        const float* b1 = gb1 + layer * 128;
        bool last = (layer == 6);

        // ---- gather phase (v2: 4 vertices/wave, 16-lane groups) ----
        for (int chunk = blockIdx.x; chunk < nchunks; chunk += gridDim.x) {
            int n0 = chunk * 16 + wave * 4;
            if (n0 < M) {
                int g = lane >> 4, c = lane & 15;
                int rp = rowptr[min(n0 + (lane & 7), M)];
                int sg = __shfl(rp, g);
                int eg = __shfl(rp, g + 1);
                int m = eg - sg;
                m = max(m, __shfl_xor(m, 16));
                m = max(m, __shfl_xor(m, 32));
                float acc[8];
#pragma unroll
                for (int j = 0; j < 8; ++j) acc[j] = 0.f;
                for (int it = 0; it < m; it += 8) {
                    int t = sg + it + (lane & 7);
                    int adjv = adj[min(t, Etot - 1)];
                    short8 buf[8];
#pragma unroll
                    for (int q = 0; q < 8; ++q) {
                        int nbq = __shfl(adjv, (lane & 48) + q);
                        buf[q] = *(const short8*)(Xin + (size_t)nbq * 128 + c * 8);
                    }
#pragma unroll
                    for (int q = 0; q < 8; ++q) {
                        bool ok = (sg + it + q < eg);
#pragma unroll
                        for (int j = 0; j < 8; ++j)
                            acc[j] += ok ? bf2f((unsigned short)buf[q][j]) : 0.f;
                    }
                }
                if (n0 + g < M) {
                    short8 o;
#pragma unroll
                    for (int j = 0; j < 8; ++j) o[j] = (short)f2bf(acc[j]);
                    *(short8*)(Agg + (size_t)(n0 + g) * 128 + c * 8) = o;
                }
            }
        }
        gridg.sync();

        // ---- GEMM phase (128-row x 64-col tiles) ----
        for (int tile = blockIdx.x; tile < ntiles; tile += gridDim.x) {
            int m0 = (tile >> 1) * 128;
            int yb = tile & 1;

            short8 axT[2][4], agT[2][4];
            int dgT[2][4];
            {
                int g = min(m0 + wrow + row16, M - 1);
#pragma unroll
                for (int ks = 0; ks < 4; ++ks) {
                    int koff = ks * 32 + quad * 8;
                    axT[0][ks] = *(const short8*)(Xin + (size_t)g * 128 + koff);
                    agT[0][ks] = *(const short8*)(Agg + (size_t)g * 128 + koff);
                }
#pragma unroll
                for (int rr = 0; rr < 4; ++rr)
                    dgT[0][rr] = degv[min(m0 + wrow + quad * 4 + rr, M - 1)];
            }

            if (tid < 64) {
                bS[tid] = b0[yb * 64 + tid];
                bS[64 + tid] = b1[yb * 64 + tid];
            }
            if (last && tid < 192) owS[tid] = ow[yb * 192 + tid];

            const unsigned short* W0h = Wt + (size_t)yb * 64 * 128;
            const unsigned short* W1h = Wt + 16384 + (size_t)yb * 64 * 128;
#pragma unroll
            for (int l = 0; l < 8; ++l) {
                int idx = tid + l * 256;
                int half = idx >> 10;
                int r = (idx >> 4) & 63;
                int c16 = idx & 15;
                int sw = (c16 ^ (r & 15)) * 8;
                const unsigned short* src = (half ? W1h : W0h) + r * 128 + c16 * 8;
                *(short8*)&wlds[half * 8192 + r * 128 + sw] = *(const short8*)src;
            }
            __syncthreads();

            {
                int g = min(m0 + 64 + wrow + row16, M - 1);
#pragma unroll
                for (int ks = 0; ks < 4; ++ks) {
                    int koff = ks * 32 + quad * 8;
                    axT[1][ks] = *(const short8*)(Xin + (size_t)g * 128 + koff);
                    agT[1][ks] = *(const short8*)(Agg + (size_t)g * 128 + koff);
                }
#pragma unroll
                for (int rr = 0; rr < 4; ++rr)
                    dgT[1][rr] = degv[min(m0 + 64 + wrow + quad * 4 + rr, M - 1)];
            }

#pragma unroll
            for (int t = 0; t < 2; ++t) {
                int mT = m0 + t * 64;
                floatx4 acc[4];
#pragma unroll
                for (int j = 0; j < 4; j++) acc[j] = (floatx4){0.f, 0.f, 0.f, 0.f};

#pragma unroll
                for (int ks = 0; ks < 4; ++ks) {
                    int c = ks * 4 + quad;
#pragma unroll
                    for (int nt = 0; nt < 4; ++nt) {
                        int wr = nt * 16 + row16;
                        short8 bw0 = *(short8*)&wlds[wr * 128 + ((c ^ row16) * 8)];
                        short8 bw1 = *(short8*)&wlds[8192 + wr * 128 + ((c ^ row16) * 8)];
                        acc[nt] = __builtin_amdgcn_mfma_f32_16x16x32_bf16(axT[t][ks], bw0,
                                                                          acc[nt], 0, 0, 0);
                        acc[nt] = __builtin_amdgcn_mfma_f32_16x16x32_bf16(agT[t][ks], bw1,
                                                                          acc[nt], 0, 0, 0);
                    }
                }

                unsigned short cvs[4][4];
#pragma unroll
                for (int nt = 0; nt < 4; ++nt) {
                    int colh = nt * 16 + row16;
                    float bc0 = bS[colh];
                    float bc1 = bS[64 + colh];
#pragma unroll
                    for (int rr = 0; rr < 4; ++rr) {
                        int row = wrow + quad * 4 + rr;
                        float v = acc[nt][rr] + bc0 + (float)dgT[t][rr] * bc1;
                        unsigned short cv = f2bf(fmaxf(v, 0.f));
                        cvs[nt][rr] = cv;
                        cs[row * 72 + colh] = cv;
                    }
                }

                if (last) {
#pragma unroll
                    for (int rr = 0; rr < 4; ++rr) {
                        float h0 = 0.f, h1 = 0.f, h2 = 0.f;
#pragma unroll
                        for (int nt = 0; nt < 4; ++nt) {
                            int colh = nt * 16 + row16;
                            float xv = bf2f(cvs[nt][rr]);
                            h0 += xv * owS[colh * 3 + 0];
                            h1 += xv * owS[colh * 3 + 1];
                            h2 += xv * owS[colh * 3 + 2];
                        }
#pragma unroll
                        for (int mm = 1; mm < 16; mm <<= 1) {
                            h0 += __shfl_xor(h0, mm);
                            h1 += __shfl_xor(h1, mm);
                            h2 += __shfl_xor(h2, mm);
                        }
                        if (row16 == 0) {
                            int gm = mT + wrow + quad * 4 + rr;
                            if (gm < M) {
                                float e0 = (yb == 0) ? ob[0] : 0.f;
                                float e1 = (yb == 0) ? ob[1] : 0.f;
                                float e2 = (yb == 0) ? ob[2] : 0.f;
                                atomicAdd(&outp[gm * 3 + 0], h0 + e0);
                                atomicAdd(&outp[gm * 3 + 1], h1 + e1);
                                atomicAdd(&outp[gm * 3 + 2], h2 + e2);
                            }
                        }
                    }
                }
                __syncthreads();

                {
                    int r = tid >> 2;
                    int cq = (tid & 3) * 16;
                    int gm = mT + r;
                    if (gm < M) {
                        unsigned short* dst = Xout + (size_t)gm * 128 + yb * 64 + cq;
                        *(short8*)dst = *(short8*)&cs[r * 72 + cq];
                        *(short8*)(dst + 8) = *(short8*)&cs[r * 72 + cq + 8];
                    }
                }
                __syncthreads();
            }
        }
        gridg.sync();
    }
}

extern "C" void kernel_launch(void* const* d_in, const int* in_sizes, int n_in, void* d_out,
                              int out_size, void* d_ws, size_t ws_size, hipStream_t stream) {
    const float* feat1 = (const float*)d_in[0];
    const float* feat2 = (const float*)d_in[1];
    const float* feat3 = (const float*)d_in[2];
    const float* feat4 = (const float*)d_in[3];
    const float* av = (const float*)d_in[4];
    const float* verts = (const float*)d_in[5];
    const float* image_enc = (const float*)d_in[6];
    const int* edges = (const int*)d_in[7];
    const float* bw = (const float*)d_in[8];
    const float* bb = (const float*)d_in[9];
    const float* g0w0 = (const float*)d_in[10];
    const float* g0b0 = (const float*)d_in[11];
    const float* g0w1 = (const float*)d_in[12];
    const float* g0b1 = (const float*)d_in[13];
    const float* gw0 = (const float*)d_in[14];
    const float* gb0 = (const float*)d_in[15];
    const float* gw1 = (const float*)d_in[16];
    const float* gb1 = (const float*)d_in[17];
    const float* off_w = (const float*)d_in[18];
    const float* off_b = (const float*)d_in[19];

    int B_ = in_sizes[6] / 256;  // 4
    int N_ = in_sizes[5] / 3;    // 40968
    int V_ = N_ / B_;            // 10242
    int E_ = in_sizes[7] / 2;    // 122880

    char* wsb = (char*)d_ws;
    size_t off = 0;
    auto alloc = [&](size_t bytes) -> void* {
        void* p = (void*)(wsb + off);
        off += (bytes + 255) & ~(size_t)255;
        return p;
    };
    int S1 = B_ * 3136 * 128;
    int S2 = B_ * 784 * 128;
    int S3 = B_ * 196 * 128;
    int S4 = B_ * 49 * 128;
    float* pp1 = (float*)alloc((size_t)S1 * 4);
    float* pp2 = (float*)alloc((size_t)S2 * 4);
    float* pp3 = (float*)alloc((size_t)S3 * 4);
    float* pp4 = (float*)alloc((size_t)S4 * 4);
    size_t pp_bytes = off;  // contiguous pp region starts at wsb
    unsigned short* fmT1 = (unsigned short*)alloc((size_t)B_ * 3136 * 256 * 2);
    unsigned short* fmT2 = (unsigned short*)alloc((size_t)B_ * 784 * 512 * 2);
    unsigned short* fmT3 = (unsigned short*)alloc((size_t)B_ * 196 * 1024 * 2);
    unsigned short* fmT4 = (unsigned short*)alloc((size_t)B_ * 49 * 2048 * 2);
    unsigned short* XA = (unsigned short*)alloc((size_t)N_ * 128 * 2);
    unsigned short* XB = (unsigned short*)alloc((size_t)N_ * 128 * 2);
    unsigned short* AggB = (unsigned short*)alloc((size_t)N_ * 128 * 2);
    unsigned short* AggH = (unsigned short*)alloc((size_t)N_ * 128 * 2);
    unsigned short* Hb = (unsigned short*)alloc((size_t)N_ * 256 * 2);
    unsigned short* Wt = (unsigned short*)alloc((size_t)8 * 2 * 128 * 128 * 2);
    unsigned short* bwT = (unsigned short*)alloc((size_t)128 * 3840 * 2);
    float* encp = (float*)alloc((size_t)2 * B_ * 128 * 4);
    int* deg = (int*)alloc((size_t)(N_ + 1) * 4);
    int* rowptr = (int*)alloc((size_t)(N_ + 1) * 4);
    int* cursor = (int*)alloc((size_t)N_ * 4);
    int* excl = (int*)alloc((size_t)N_ * 4);
    int* bsum = (int*)alloc((size_t)64 * 4);
    int* adj = (int*)alloc((size_t)2 * E_ * 4);

    hipMemsetAsync(deg, 0, (N_ + 1) * sizeof(int), stream);
    hipMemsetAsync(wsb, 0, pp_bytes, stream);    // zero pp for atomic accumulation
    hipMemsetAsync(d_out, 0, out_size, stream);  // zero out for fused-head atomics

    // fat prologue: count_deg | prep_w | prep_bwT | enc_proj | fm transpose
    int nE = ceil_div(E_, 256);
    int NT = (49 * 4 + 13 * 8 + 4 * 16 + 1 * 32) * B_;  // 1584 transpose tiles
    fatpre_k<<<nE + 46 + B_ + NT, 256, 0, stream>>>(
        edges, deg, E_, nE, g0w0, g0w1, gw0, gw1, Wt, bw, bwT, image_enc, encp, feat1, feat2,
        feat3, feat4, fmT1, fmT2, fmT3, fmT4, B_);

    // CSR scan + fill
    int nb = ceil_div(N_, 1024);
    scan1_k<<<nb, 1024, 0, stream>>>(deg, excl, bsum, N_);
    scan3_k<<<nb, 1024, 0, stream>>>(excl, bsum, deg, rowptr, cursor, N_, nb);
    fill_adj_k<<<ceil_div(E_, 256), 256, 0, stream>>>(edges, cursor, adj, E_);

    // pixel projection via MFMA (K<=256 per block, direct bf16 A-loads, atomic into pp)
    int nproj = 49 * B_ * 2 + 13 * B_ * 2 + 4 * B_ * 4 + 1 * B_ * 8;
    proj_all_k<<<nproj, 256, 0, stream>>>(fmT1, fmT2, fmT3, fmT4, bwT, pp1, pp2, pp3, pp4,
                                          B_);

    // sample + bottleneck -> XA (bf16 X0); layer0 pre terms (biases baked) -> Hb (bf16)
    sample_bottleneck_k<<<ceil_div(N_, 4), 256, 0, stream>>>(
        av, pp1, pp2, pp3, pp4, bb, verts, encp, g0w0, g0w1, g0b0, g0b1, XA, Hb, N_, V_, B_);

    // layer 0 (split): v2 adj walk gathers X-sums AND (h0 + h1-sums)
    dim3 ggrid(ceil_div(N_, 128), 2);
    int agrid4 = ceil_div(N_, 16);
    agg0_k<<<agrid4, 256, 0, stream>>>(XA, Hb, rowptr, adj, AggB, AggH, N_, 2 * E_);
    gemm_dual_k<<<ggrid, 256, 0, stream>>>(XA, AggB, Wt, nullptr, nullptr, AggH, deg, XB, N_);

    // layers 1..7: single cooperative persistent kernel (phase-alternating)
    {
        int maxb = 0;
        hipOccupancyMaxActiveBlocksPerMultiprocessor(&maxb, layers_coop_k, 256, 0);
        if (maxb < 1) maxb = 1;
        int dev = 0;
        hipGetDevice(&dev);
        int ncu = 0;
        hipDeviceGetAttribute(&ncu, hipDeviceAttributeMultiprocessorCount, dev);
        if (ncu < 1) ncu = 256;
        int G = maxb * ncu;
        int nchunks = ceil_div(N_, 16);
        if (G > nchunks) G = nchunks;

        unsigned short* X0 = XB;  // input to first coop layer
        unsigned short* X1 = XA;
        int Etot = 2 * E_;
        float* outp = (float*)d_out;
        void* cargs[] = {&X0,  &X1,   &rowptr, &adj,   &Wt, &gb0,    &gb1,
                         &AggB, &deg, &N_,     &Etot,  &off_w, &off_b, &outp};
        hipLaunchCooperativeKernel(layers_coop_k, dim3(G), dim3(256), cargs, 0, stream);
    }
}

// Round 13
// 430.067 us; speedup vs baseline: 2.3041x; 2.3041x over previous
//
#include <hip/hip_runtime.h>

static inline int ceil_div(int a, int b) { return (a + b - 1) / b; }

typedef __attribute__((ext_vector_type(8))) short short8;
typedef __attribute__((ext_vector_type(4))) float floatx4;

__device__ __forceinline__ unsigned short f2bf(float f) {
    unsigned int u = __float_as_uint(f);
    unsigned int r = (u + 0x7fffu + ((u >> 16) & 1u)) >> 16;
    return (unsigned short)r;
}
__device__ __forceinline__ float bf2f(unsigned short h) {
    return __uint_as_float(((unsigned int)h) << 16);
}

// ---------------- CSR scan ----------------
__global__ __launch_bounds__(1024) void scan1_k(const int* __restrict__ deg,
                                                int* __restrict__ excl,
                                                int* __restrict__ bsum, int Nv) {
    __shared__ int s[1024];
    int tid = threadIdx.x;
    int i = blockIdx.x * 1024 + tid;
    int v = (i < Nv) ? deg[i] : 0;
    s[tid] = v;
    __syncthreads();
    for (int off = 1; off < 1024; off <<= 1) {
        int t = (tid >= off) ? s[tid - off] : 0;
        __syncthreads();
        if (tid >= off) s[tid] += t;
        __syncthreads();
    }
    if (i < Nv) excl[i] = s[tid] - v;
    if (tid == 1023) bsum[blockIdx.x] = s[1023];
}

// scan3 with inline block-offset prefix (replaces scan2+scan3; nb <= 64)
__global__ __launch_bounds__(1024) void scan3_k(const int* __restrict__ excl,
                                                const int* __restrict__ bsum,
                                                const int* __restrict__ deg,
                                                int* __restrict__ rowptr,
                                                int* __restrict__ cursor, int Nv, int nb) {
    __shared__ int offS;
    if (threadIdx.x < 64) {
        int v = (threadIdx.x < min((int)blockIdx.x, nb)) ? bsum[threadIdx.x] : 0;
#pragma unroll
        for (int m = 1; m < 64; m <<= 1) v += __shfl_xor(v, m);
        if (threadIdx.x == 0) offS = v;
    }
    __syncthreads();
    int i = blockIdx.x * 1024 + threadIdx.x;
    if (i < Nv) {
        int val = excl[i] + offS;
        rowptr[i] = val;
        cursor[i] = val;
        if (i == Nv - 1) rowptr[Nv] = val + deg[i];
    }
}

__global__ __launch_bounds__(256) void fill_adj_k(const int* __restrict__ edges,
                                                  int* __restrict__ cursor,
                                                  int* __restrict__ adj, int E) {
    int e = blockIdx.x * blockDim.x + threadIdx.x;
    if (e < E) {
        int a = edges[2 * e], b = edges[2 * e + 1];
        adj[atomicAdd(&cursor[a], 1)] = b;
        adj[atomicAdd(&cursor[b], 1)] = a;
    }
}

// ---------------- fat prologue: count_deg | prep_w | prep_bwT | enc_proj ----------------
__global__ __launch_bounds__(256) void fatpre_k(const int* __restrict__ edges,
                                                int* __restrict__ deg, int E, int nE,
                                                const float* __restrict__ g0w0,
                                                const float* __restrict__ g0w1,
                                                const float* __restrict__ gw0,
                                                const float* __restrict__ gw1,
                                                unsigned short* __restrict__ Wt,
                                                const float* __restrict__ bw,
                                                unsigned short* __restrict__ bwT,
                                                const float* __restrict__ enc,
                                                float* __restrict__ encp, int B_) {
    int bid = blockIdx.x;
    int tid = threadIdx.x;
    if (bid < nE) {
        int e = bid * 256 + tid;
        if (e < E) {
            atomicAdd(&deg[edges[2 * e]], 1);
            atomicAdd(&deg[edges[2 * e + 1]], 1);
        }
    } else if (bid < nE + 16) {
        int lh = bid - nE;
        int l = lh >> 1, h = lh & 1;
        const float* src;
        if (l == 0) src = h ? g0w1 : g0w0;
        else src = (h ? gw1 : gw0) + (size_t)(l - 1) * 16384;
        unsigned short* dst = Wt + (size_t)lh * 16384;
        for (int idx = tid; idx < 16384; idx += 256) {
            int n = idx >> 7, k = idx & 127;
            dst[n * 128 + k] = f2bf(src[k * 128 + n]);
        }
    } else if (bid < nE + 46) {
        // bottleneck weight transpose+cast: bwT[n][k] = bf16(bw[k][n])
        int blk = bid - nE - 16;  // 0..29
        for (int idx = tid; idx < 16384; idx += 256) {
            int n = idx >> 7, kk = idx & 127;
            bwT[(size_t)n * 3840 + blk * 128 + kk] =
                f2bf(bw[(size_t)(blk * 128 + kk) * 128 + n]);
        }
    } else {
        int b = bid - nE - 46;
        int sH = tid >> 7;
        int j = tid & 127;
        const float* w = sH ? g0w1 : g0w0;
        const float* eb = enc + b * 256;
        float acc = 0.f;
        for (int c = 0; c < 256; ++c) acc = fmaf(eb[c], w[(131 + c) * 128 + j], acc);
        encp[(sH * B_ + b) * 128 + j] = acc;
    }
}

// ---------------- pixel projection via MFMA (K=128 per block, atomic accumulate) ----------------
__global__ __launch_bounds__(256) void proj_all_k(
    const float* __restrict__ fm1, const float* __restrict__ fm2,
    const float* __restrict__ fm3, const float* __restrict__ fm4,
    const unsigned short* __restrict__ bwT, float* __restrict__ o1, float* __restrict__ o2,
    float* __restrict__ o3, float* __restrict__ o4, int B_) {
    __shared__ unsigned short wlds[8192];  // 16 KB: [128 n][64 k] bf16, XOR-swizzled

    int tid = threadIdx.x;
    int n1 = 49 * B_ * 2, n2 = 13 * B_ * 4, n3 = 4 * B_ * 8;
    int bid = blockIdx.x;
    const float* fm;
    float* op;
    int C, HW, PT, idx, koff;
    if (bid < n1) {
        fm = fm1; op = o1; C = 256; HW = 3136; PT = 49; idx = bid; koff = 0;
    } else if (bid < n1 + n2) {
        fm = fm2; op = o2; C = 512; HW = 784; PT = 13; idx = bid - n1; koff = 256;
    } else if (bid < n1 + n2 + n3) {
        fm = fm3; op = o3; C = 1024; HW = 196; PT = 4; idx = bid - n1 - n2; koff = 768;
    } else {
        fm = fm4; op = o4; C = 2048; HW = 49; PT = 1; idx = bid - n1 - n2 - n3; koff = 1792;
    }
    int pt = idx % PT;
    int r2 = idx / PT;
    int b = r2 % B_;
    int zz = r2 / B_;
    int p0 = pt * 64;
    const float* fmb = fm + (size_t)b * C * HW;
    int kcf0 = zz * 128;  // this block's 128-wide channel window

    int wave = tid >> 6, lane = tid & 63;
    int row16 = lane & 15, quad = lane >> 4;
    int p = p0 + wave * 16 + row16;
    bool pok = (p < HW);
    int pc = pok ? p : 0;

    floatx4 acc[8];
#pragma unroll
    for (int j = 0; j < 8; ++j) acc[j] = (floatx4){0.f, 0.f, 0.f, 0.f};

#pragma unroll
    for (int zz2 = 0; zz2 < 2; ++zz2) {
        int kcf = kcf0 + zz2 * 64;
        int kcw = koff + kcf;
        if (zz2) __syncthreads();  // protect previous chunk's wlds reads
        // stage W^T tile [128 n][64 k] bf16, swizzled
#pragma unroll
        for (int l = 0; l < 4; ++l) {
            int i2 = tid + l * 256;  // 0..1023
            int n = i2 >> 3, c16 = i2 & 7;
            *(short8*)&wlds[n * 64 + ((c16 ^ (n & 7)) * 8)] =
                *(const short8*)(bwT + (size_t)n * 3840 + kcw + c16 * 8);
        }
        short8 ax[2];
#pragma unroll
        for (int ks = 0; ks < 2; ++ks) {
#pragma unroll
            for (int j = 0; j < 8; ++j) {
                float v = pok ? fmb[(size_t)(kcf + ks * 32 + quad * 8 + j) * HW + pc] : 0.f;
                ax[ks][j] = (short)f2bf(v);
            }
        }
        __syncthreads();
#pragma unroll
        for (int ks = 0; ks < 2; ++ks) {
            int c = ks * 4 + quad;
#pragma unroll
            for (int nt = 0; nt < 8; ++nt) {
                int wr = nt * 16 + row16;
                short8 bwf = *(short8*)&wlds[wr * 64 + ((c ^ (wr & 7)) * 8)];
                acc[nt] =
                    __builtin_amdgcn_mfma_f32_16x16x32_bf16(ax[ks], bwf, acc[nt], 0, 0, 0);
            }
        }
    }

    float* obase = op + (size_t)b * HW * 128;
#pragma unroll
    for (int nt = 0; nt < 8; ++nt) {
        int colg = nt * 16 + row16;
#pragma unroll
        for (int rr = 0; rr < 4; ++rr) {
            int pr = p0 + wave * 16 + quad * 4 + rr;
            if (pr < HW) atomicAdd(&obase[(size_t)pr * 128 + colg], acc[nt][rr]);
        }
    }
}

// ---------------- bilinear sample + bottleneck relu + layer0 pre terms ----------------
__device__ __forceinline__ float sample_level(const float* __restrict__ pp, int Hh, int Ww,
                                              float gx, float gy, int j) {
    float x = (gx + 1.f) * 0.5f * (float)(Ww - 1);
    float y = (gy + 1.f) * 0.5f * (float)(Hh - 1);
    float x0f = floorf(x), y0f = floorf(y);
    float wx1 = x - x0f, wy1 = y - y0f;
    float wx0 = 1.f - wx1, wy0 = 1.f - wy1;
    int x0 = (int)fminf(fmaxf(x0f, 0.f), (float)(Ww - 1));
    int x1 = (int)fminf(fmaxf(x0f + 1.f, 0.f), (float)(Ww - 1));
    int y0 = (int)fminf(fmaxf(y0f, 0.f), (float)(Hh - 1));
    int y1 = (int)fminf(fmaxf(y0f + 1.f, 0.f), (float)(Hh - 1));
    const float* r00 = pp + (size_t)(y0 * Ww + x0) * 128;
    const float* r01 = pp + (size_t)(y0 * Ww + x1) * 128;
    const float* r10 = pp + (size_t)(y1 * Ww + x0) * 128;
    const float* r11 = pp + (size_t)(y1 * Ww + x1) * 128;
    return wy0 * (wx0 * r00[j] + wx1 * r01[j]) + wy1 * (wx0 * r10[j] + wx1 * r11[j]);
}

__global__ __launch_bounds__(128) void sample_bottleneck_k(
    const float* __restrict__ av, const float* __restrict__ pp1, const float* __restrict__ pp2,
    const float* __restrict__ pp3, const float* __restrict__ pp4, const float* __restrict__ bb,
    const float* __restrict__ verts, const float* __restrict__ encp,
    const float* __restrict__ g0w0, const float* __restrict__ g0w1,
    const float* __restrict__ g0b0, const float* __restrict__ g0b1,
    unsigned short* __restrict__ X, unsigned short* __restrict__ H, int V_, int B_) {
    int n = blockIdx.x, j = threadIdx.x;
    int b = n / V_;
    float gx = av[(size_t)n * 3 + 0];
    float gy = av[(size_t)n * 3 + 1];
    float acc = bb[j];
    acc += sample_level(pp1 + (size_t)b * 3136 * 128, 56, 56, gx, gy, j);
    acc += sample_level(pp2 + (size_t)b * 784 * 128, 28, 28, gx, gy, j);
    acc += sample_level(pp3 + (size_t)b * 196 * 128, 14, 14, gx, gy, j);
    acc += sample_level(pp4 + (size_t)b * 49 * 128, 7, 7, gx, gy, j);
    X[(size_t)n * 128 + j] = f2bf(fmaxf(acc, 0.f));
    float v0 = verts[n * 3 + 0], v1 = verts[n * 3 + 1], v2 = verts[n * 3 + 2];
    float h0 = encp[(0 * B_ + b) * 128 + j] + g0b0[j] + v0 * g0w0[128 * 128 + j] +
               v1 * g0w0[129 * 128 + j] + v2 * g0w0[130 * 128 + j];
    float h1 = encp[(1 * B_ + b) * 128 + j] + g0b1[j] + v0 * g0w1[128 * 128 + j] +
               v1 * g0w1[129 * 128 + j] + v2 * g0w1[130 * 128 + j];
    H[(size_t)n * 256 + j] = f2bf(h0);
    H[(size_t)n * 256 + 128 + j] = f2bf(h1);
}

// ---------------- layer-0 gather v2: 4 vertices/wave, AggX=sum X, AggH=h0+sum h1 -------
// Same instruction-quartered structure as agg_x_k; X and H rows fetched in the
// same batched walk; vertex's own h0 folded into AggH init.
__global__ __launch_bounds__(256) void agg0_k(const unsigned short* __restrict__ X,
                                              const unsigned short* __restrict__ H,
                                              const int* __restrict__ rowptr,
                                              const int* __restrict__ adj,
                                              unsigned short* __restrict__ AggX,
                                              unsigned short* __restrict__ AggH, int Nv,
                                              int Etot) {
    int wave = threadIdx.x >> 6, lane = threadIdx.x & 63;
    int n0 = (blockIdx.x * 4 + wave) * 4;
    if (n0 >= Nv) return;
    int g = lane >> 4, c = lane & 15;
    int rp = rowptr[min(n0 + (lane & 7), Nv)];
    int sg = __shfl(rp, g);
    int eg = __shfl(rp, g + 1);
    int m = eg - sg;
    m = max(m, __shfl_xor(m, 16));
    m = max(m, __shfl_xor(m, 32));

    int n = n0 + g;
    bool nok = (n < Nv);
    int nc = nok ? n : (Nv - 1);
    float accx[8], acch[8];
    short8 h0v = *(const short8*)(H + (size_t)nc * 256 + c * 8);
#pragma unroll
    for (int j = 0; j < 8; ++j) {
        accx[j] = 0.f;
        acch[j] = bf2f((unsigned short)h0v[j]);
    }

    for (int it = 0; it < m; it += 8) {
        int t = sg + it + (lane & 7);
        int adjv = adj[min(t, Etot - 1)];
        short8 bx[8], bh[8];
#pragma unroll
        for (int q = 0; q < 8; ++q) {
            int nbq = __shfl(adjv, (lane & 48) + q);
            bx[q] = *(const short8*)(X + (size_t)nbq * 128 + c * 8);
            bh[q] = *(const short8*)(H + (size_t)nbq * 256 + 128 + c * 8);
        }
#pragma unroll
        for (int q = 0; q < 8; ++q) {
            bool ok = (sg + it + q < eg);
#pragma unroll
            for (int j = 0; j < 8; ++j) {
                accx[j] += ok ? bf2f((unsigned short)bx[q][j]) : 0.f;
                acch[j] += ok ? bf2f((unsigned short)bh[q][j]) : 0.f;
            }
        }
    }
    if (nok) {
        short8 ox, oh;
#pragma unroll
        for (int j = 0; j < 8; ++j) {
            ox[j] = (short)f2bf(accx[j]);
            oh[j] = (short)f2bf(acch[j]);
        }
        *(short8*)(AggX + (size_t)n * 128 + c * 8) = ox;
        *(short8*)(AggH + (size_t)n * 128 + c * 8) = oh;
    }
}

// ---------------- gather v2: 4 vertices/wave, 16-lane groups, short8 lane loads ----------
__global__ __launch_bounds__(256) void agg_x_k(const unsigned short* __restrict__ X,
                                               const int* __restrict__ rowptr,
                                               const int* __restrict__ adj,
                                               unsigned short* __restrict__ Agg, int Nv,
                                               int Etot) {
    int wave = threadIdx.x >> 6, lane = threadIdx.x & 63;
    int n0 = (blockIdx.x * 4 + wave) * 4;
    if (n0 >= Nv) return;
    int g = lane >> 4, c = lane & 15;
    int rp = rowptr[min(n0 + (lane & 7), Nv)];  // lanes 0..4 meaningful
    int sg = __shfl(rp, g);
    int eg = __shfl(rp, g + 1);
    int m = eg - sg;
    m = max(m, __shfl_xor(m, 16));
    m = max(m, __shfl_xor(m, 32));  // max degree over the 4 groups

    float acc[8];
#pragma unroll
    for (int j = 0; j < 8; ++j) acc[j] = 0.f;

    for (int it = 0; it < m; it += 8) {
        int t = sg + it + (lane & 7);
        int adjv = adj[min(t, Etot - 1)];
        short8 buf[8];
#pragma unroll
        for (int q = 0; q < 8; ++q) {
            int nbq = __shfl(adjv, (lane & 48) + q);  // group base lane + q
            buf[q] = *(const short8*)(X + (size_t)nbq * 128 + c * 8);
        }
#pragma unroll
        for (int q = 0; q < 8; ++q) {
            bool ok = (sg + it + q < eg);
#pragma unroll
            for (int j = 0; j < 8; ++j) {
                float v = bf2f((unsigned short)buf[q][j]);
                acc[j] += ok ? v : 0.f;
            }
        }
    }

    if (n0 + g < Nv) {
        short8 o;
#pragma unroll
        for (int j = 0; j < 8; ++j) o[j] = (short)f2bf(acc[j]);
        *(short8*)(Agg + (size_t)(n0 + g) * 128 + c * 8) = o;
    }
}

// ---------------- dual-MFMA layer GEMM: 128-row x 64-col tiles ----------------
// Layer 0: aggh (h0 + gathered h1 sums) supplies the affine terms.
// Last layer: head fused -- out[gm] += sum_col relu(x)[gm,col] * off_w[col,:].
__global__ __launch_bounds__(256, 3) void gemm_dual_k(
    const unsigned short* __restrict__ Xin, const unsigned short* __restrict__ Agg,
    const unsigned short* __restrict__ Wt,  // [2][128][128] bf16 n-major (W0, W1)
    const float* __restrict__ b0, const float* __restrict__ b1,
    const unsigned short* __restrict__ aggh, const int* __restrict__ degv,
    unsigned short* __restrict__ Xout, int M, const float* __restrict__ ow,
    const float* __restrict__ ob, float* __restrict__ outp) {
    __shared__ unsigned short wlds[16384];  // 32 KB weights (stays live both sub-tiles)
    __shared__ unsigned short cs[64 * 72];  // 9 KB epilogue staging
    __shared__ float bS[128];
    __shared__ float owS[192];  // head weights for this yb half

    int tid = threadIdx.x;
    int m0 = blockIdx.x * 128;
    int yb = blockIdx.y;

    int wave = tid >> 6, lane = tid & 63;
    int row16 = lane & 15;
    int quad = lane >> 4;
    int wrow = wave * 16;

    // prefetch A + deg for sub-tile 0 (overlaps weight staging)
    short8 axT[2][4], agT[2][4];
    int dgT[2][4];
    {
        int g = min(m0 + wrow + row16, M - 1);
#pragma unroll
        for (int ks = 0; ks < 4; ++ks) {
            int koff = ks * 32 + quad * 8;
            axT[0][ks] = *(const short8*)(Xin + (size_t)g * 128 + koff);
            agT[0][ks] = *(const short8*)(Agg + (size_t)g * 128 + koff);
        }
#pragma unroll
        for (int rr = 0; rr < 4; ++rr)
            dgT[0][rr] = degv[min(m0 + wrow + quad * 4 + rr, M - 1)];
    }

    if (tid < 64) {
        bS[tid] = b0 ? b0[yb * 64 + tid] : 0.f;
        bS[64 + tid] = b1 ? b1[yb * 64 + tid] : 0.f;
    }
    if (outp && tid < 192) owS[tid] = ow[yb * 192 + tid];

    const unsigned short* W0h = Wt + (size_t)yb * 64 * 128;
    const unsigned short* W1h = Wt + 16384 + (size_t)yb * 64 * 128;
#pragma unroll
    for (int l = 0; l < 8; ++l) {
        int idx = tid + l * 256;      // 0..2047 16B chunks
        int half = idx >> 10;
        int r = (idx >> 4) & 63;
        int c16 = idx & 15;
        int sw = (c16 ^ (r & 15)) * 8;
        const unsigned short* src = (half ? W1h : W0h) + r * 128 + c16 * 8;
        *(short8*)&wlds[half * 8192 + r * 128 + sw] = *(const short8*)src;
    }
    __syncthreads();

    // prefetch A + deg for sub-tile 1 (overlaps sub-tile-0 MFMA)
    {
        int g = min(m0 + 64 + wrow + row16, M - 1);
#pragma unroll
        for (int ks = 0; ks < 4; ++ks) {
            int koff = ks * 32 + quad * 8;
            axT[1][ks] = *(const short8*)(Xin + (size_t)g * 128 + koff);
            agT[1][ks] = *(const short8*)(Agg + (size_t)g * 128 + koff);
        }
#pragma unroll
        for (int rr = 0; rr < 4; ++rr)
            dgT[1][rr] = degv[min(m0 + 64 + wrow + quad * 4 + rr, M - 1)];
    }

#pragma unroll
    for (int t = 0; t < 2; ++t) {
        int mT = m0 + t * 64;
        floatx4 acc[4];
#pragma unroll
        for (int j = 0; j < 4; j++) acc[j] = (floatx4){0.f, 0.f, 0.f, 0.f};

#pragma unroll
        for (int ks = 0; ks < 4; ++ks) {
            int c = ks * 4 + quad;
#pragma unroll
            for (int nt = 0; nt < 4; ++nt) {
                int wr = nt * 16 + row16;
                short8 bw0 = *(short8*)&wlds[wr * 128 + ((c ^ row16) * 8)];
                short8 bw1 = *(short8*)&wlds[8192 + wr * 128 + ((c ^ row16) * 8)];
                acc[nt] = __builtin_amdgcn_mfma_f32_16x16x32_bf16(axT[t][ks], bw0, acc[nt], 0, 0, 0);
                acc[nt] = __builtin_amdgcn_mfma_f32_16x16x32_bf16(agT[t][ks], bw1, acc[nt], 0, 0, 0);
            }
        }

        // epilogue -> cs (each wave writes its own 16 rows)
        unsigned short cvs[4][4];
#pragma unroll
        for (int nt = 0; nt < 4; ++nt) {
            int colh = nt * 16 + row16;
            int colg = yb * 64 + colh;
            float bc0 = bS[colh];
            float bc1 = bS[64 + colh];
#pragma unroll
            for (int rr = 0; rr < 4; ++rr) {
                int row = wrow + quad * 4 + rr;
                int gm = mT + row;
                float v = acc[nt][rr] + bc0 + (float)dgT[t][rr] * bc1;
                if (aggh && gm < M) v += bf2f(aggh[(size_t)gm * 128 + colg]);
                unsigned short cv = f2bf(fmaxf(v, 0.f));
                cvs[nt][rr] = cv;
                cs[row * 72 + colh] = cv;
            }
        }

        // fused head (last layer only): per-row 3-dot over this yb half
        if (outp) {
#pragma unroll
            for (int rr = 0; rr < 4; ++rr) {
                float h0 = 0.f, h1 = 0.f, h2 = 0.f;
#pragma unroll
                for (int nt = 0; nt < 4; ++nt) {
                    int colh = nt * 16 + row16;
                    float xv = bf2f(cvs[nt][rr]);
                    h0 += xv * owS[colh * 3 + 0];
                    h1 += xv * owS[colh * 3 + 1];
                    h2 += xv * owS[colh * 3 + 2];
                }
#pragma unroll
                for (int mm = 1; mm < 16; mm <<= 1) {
                    h0 += __shfl_xor(h0, mm);
                    h1 += __shfl_xor(h1, mm);
                    h2 += __shfl_xor(h2, mm);
                }
                if (row16 == 0) {
                    int gm = mT + wrow + quad * 4 + rr;
                    if (gm < M) {
                        float e0 = (yb == 0) ? ob[0] : 0.f;
                        float e1 = (yb == 0) ? ob[1] : 0.f;
                        float e2 = (yb == 0) ? ob[2] : 0.f;
                        atomicAdd(&outp[gm * 3 + 0], h0 + e0);
                        atomicAdd(&outp[gm * 3 + 1], h1 + e1);
                        atomicAdd(&outp[gm * 3 + 2], h2 + e2);
                    }
                }
            }
        }
        __syncthreads();

        // coalesced copy-out
        {
            int r = tid >> 2;
            int cq = (tid & 3) * 16;
            int gm = mT + r;
            if (gm < M) {
                unsigned short* dst = Xout + (size_t)gm * 128 + yb * 64 + cq;
                *(short8*)dst = *(short8*)&cs[r * 72 + cq];
                *(short8*)(dst + 8) = *(short8*)&cs[r * 72 + cq + 8];
            }
        }
        __syncthreads();  // cs reads done before next sub-tile overwrites
    }
}

extern "C" void kernel_launch(void* const* d_in, const int* in_sizes, int n_in, void* d_out,
                              int out_size, void* d_ws, size_t ws_size, hipStream_t stream) {
    const float* feat1 = (const float*)d_in[0];
    const float* feat2 = (const float*)d_in[1];
    const float* feat3 = (const float*)d_in[2];
    const float* feat4 = (const float*)d_in[3];
    const float* av = (const float*)d_in[4];
    const float* verts = (const float*)d_in[5];
    const float* image_enc = (const float*)d_in[6];
    const int* edges = (const int*)d_in[7];
    const float* bw = (const float*)d_in[8];
    const float* bb = (const float*)d_in[9];
    const float* g0w0 = (const float*)d_in[10];
    const float* g0b0 = (const float*)d_in[11];
    const float* g0w1 = (const float*)d_in[12];
    const float* g0b1 = (const float*)d_in[13];
    const float* gw0 = (const float*)d_in[14];
    const float* gb0 = (const float*)d_in[15];
    const float* gw1 = (const float*)d_in[16];
    const float* gb1 = (const float*)d_in[17];
    const float* off_w = (const float*)d_in[18];
    const float* off_b = (const float*)d_in[19];

    int B_ = in_sizes[6] / 256;  // 4
    int N_ = in_sizes[5] / 3;    // 40968
    int V_ = N_ / B_;            // 10242
    int E_ = in_sizes[7] / 2;    // 122880

    char* wsb = (char*)d_ws;
    size_t off = 0;
    auto alloc = [&](size_t bytes) -> void* {
        void* p = (void*)(wsb + off);
        off += (bytes + 255) & ~(size_t)255;
        return p;
    };
    int S1 = B_ * 3136 * 128;
    int S2 = B_ * 784 * 128;
    int S3 = B_ * 196 * 128;
    int S4 = B_ * 49 * 128;
    float* pp1 = (float*)alloc((size_t)S1 * 4);
    float* pp2 = (float*)alloc((size_t)S2 * 4);
    float* pp3 = (float*)alloc((size_t)S3 * 4);
    float* pp4 = (float*)alloc((size_t)S4 * 4);
    size_t pp_bytes = off;  // contiguous pp region starts at wsb
    unsigned short* XA = (unsigned short*)alloc((size_t)N_ * 128 * 2);
    unsigned short* XB = (unsigned short*)alloc((size_t)N_ * 128 * 2);
    unsigned short* AggB = (unsigned short*)alloc((size_t)N_ * 128 * 2);
    unsigned short* AggH = (unsigned short*)alloc((size_t)N_ * 128 * 2);
    unsigned short* Hb = (unsigned short*)alloc((size_t)N_ * 256 * 2);
    unsigned short* Wt = (unsigned short*)alloc((size_t)8 * 2 * 128 * 128 * 2);
    unsigned short* bwT = (unsigned short*)alloc((size_t)128 * 3840 * 2);
    float* encp = (float*)alloc((size_t)2 * B_ * 128 * 4);
    int* deg = (int*)alloc((size_t)(N_ + 1) * 4);
    int* rowptr = (int*)alloc((size_t)(N_ + 1) * 4);
    int* cursor = (int*)alloc((size_t)N_ * 4);
    int* excl = (int*)alloc((size_t)N_ * 4);
    int* bsum = (int*)alloc((size_t)64 * 4);
    int* adj = (int*)alloc((size_t)2 * E_ * 4);

    hipMemsetAsync(deg, 0, (N_ + 1) * sizeof(int), stream);
    hipMemsetAsync(wsb, 0, pp_bytes, stream);    // zero pp for atomic accumulation
    hipMemsetAsync(d_out, 0, out_size, stream);  // zero out for fused-head atomics

    // fat prologue: count_deg | prep_w | prep_bwT | enc_proj
    int nE = ceil_div(E_, 256);
    fatpre_k<<<nE + 46 + B_, 256, 0, stream>>>(edges, deg, E_, nE, g0w0, g0w1, gw0, gw1, Wt,
                                               bw, bwT, image_enc, encp, B_);

    // CSR scan + fill
    int nb = ceil_div(N_, 1024);
    scan1_k<<<nb, 1024, 0, stream>>>(deg, excl, bsum, N_);
    scan3_k<<<nb, 1024, 0, stream>>>(excl, bsum, deg, rowptr, cursor, N_, nb);
    fill_adj_k<<<ceil_div(E_, 256), 256, 0, stream>>>(edges, cursor, adj, E_);

    // pixel projection via MFMA (K=128 per block, atomic accumulate into pp)
    int nproj = 49 * B_ * 2 + 13 * B_ * 4 + 4 * B_ * 8 + 1 * B_ * 16;
    proj_all_k<<<nproj, 256, 0, stream>>>(feat1, feat2, feat3, feat4, bwT, pp1, pp2, pp3, pp4,
                                          B_);

    // sample + bottleneck -> XA (bf16 X0); layer0 pre terms (biases baked) -> Hb (bf16)
    sample_bottleneck_k<<<N_, 128, 0, stream>>>(av, pp1, pp2, pp3, pp4, bb, verts, encp, g0w0,
                                                g0w1, g0b0, g0b1, XA, Hb, V_, B_);

    dim3 ggrid(ceil_div(N_, 128), 2);
    int agrid4 = ceil_div(N_, 16);
    // layer 0: one v2 adj walk gathers X-sums AND (h0 + h1-sums); epilogue adds AggH
    agg0_k<<<agrid4, 256, 0, stream>>>(XA, Hb, rowptr, adj, AggB, AggH, N_, 2 * E_);
    gemm_dual_k<<<ggrid, 256, 0, stream>>>(XA, AggB, Wt, nullptr, nullptr, AggH, deg, XB, N_,
                                           nullptr, nullptr, nullptr);
    unsigned short* Xc = XB;
    unsigned short* Xn = XA;
    for (int i = 0; i < 7; ++i) {
        bool last = (i == 6);
        agg_x_k<<<agrid4, 256, 0, stream>>>(Xc, rowptr, adj, AggB, N_, 2 * E_);
        gemm_dual_k<<<ggrid, 256, 0, stream>>>(Xc, AggB, Wt + (size_t)(i + 1) * 32768,
                                               gb0 + i * 128, gb1 + i * 128, nullptr, deg, Xn,
                                               N_, last ? off_w : nullptr,
                                               last ? off_b : nullptr,
                                               last ? (float*)d_out : nullptr);
        unsigned short* t = Xc;
        Xc = Xn;
        Xn = t;
    }
}

// Round 14
// 429.821 us; speedup vs baseline: 2.3054x; 1.0006x over previous
//
#include <hip/hip_runtime.h>

static inline int ceil_div(int a, int b) { return (a + b - 1) / b; }

typedef __attribute__((ext_vector_type(8))) short short8;
typedef __attribute__((ext_vector_type(4))) float floatx4;

__device__ __forceinline__ unsigned short f2bf(float f) {
    unsigned int u = __float_as_uint(f);
    unsigned int r = (u + 0x7fffu + ((u >> 16) & 1u)) >> 16;
    return (unsigned short)r;
}
__device__ __forceinline__ float bf2f(unsigned short h) {
    return __uint_as_float(((unsigned int)h) << 16);
}

// ---------------- CSR scan ----------------
__global__ __launch_bounds__(1024) void scan1_k(const int* __restrict__ deg,
                                                int* __restrict__ excl,
                                                int* __restrict__ bsum, int Nv) {
    __shared__ int s[1024];
    int tid = threadIdx.x;
    int i = blockIdx.x * 1024 + tid;
    int v = (i < Nv) ? deg[i] : 0;
    s[tid] = v;
    __syncthreads();
    for (int off = 1; off < 1024; off <<= 1) {
        int t = (tid >= off) ? s[tid - off] : 0;
        __syncthreads();
        if (tid >= off) s[tid] += t;
        __syncthreads();
    }
    if (i < Nv) excl[i] = s[tid] - v;
    if (tid == 1023) bsum[blockIdx.x] = s[1023];
}

// scan3 with inline block-offset prefix (replaces scan2+scan3; nb <= 64)
__global__ __launch_bounds__(1024) void scan3_k(const int* __restrict__ excl,
                                                const int* __restrict__ bsum,
                                                const int* __restrict__ deg,
                                                int* __restrict__ rowptr,
                                                int* __restrict__ cursor, int Nv, int nb) {
    __shared__ int offS;
    if (threadIdx.x < 64) {
        int v = (threadIdx.x < min((int)blockIdx.x, nb)) ? bsum[threadIdx.x] : 0;
#pragma unroll
        for (int m = 1; m < 64; m <<= 1) v += __shfl_xor(v, m);
        if (threadIdx.x == 0) offS = v;
    }
    __syncthreads();
    int i = blockIdx.x * 1024 + threadIdx.x;
    if (i < Nv) {
        int val = excl[i] + offS;
        rowptr[i] = val;
        cursor[i] = val;
        if (i == Nv - 1) rowptr[Nv] = val + deg[i];
    }
}

__global__ __launch_bounds__(256) void fill_adj_k(const int* __restrict__ edges,
                                                  int* __restrict__ cursor,
                                                  int* __restrict__ adj, int E) {
    int e = blockIdx.x * blockDim.x + threadIdx.x;
    if (e < E) {
        int a = edges[2 * e], b = edges[2 * e + 1];
        adj[atomicAdd(&cursor[a], 1)] = b;
        adj[atomicAdd(&cursor[b], 1)] = a;
    }
}

// ---------------- fat prologue: count_deg | prep_w | prep_bwT | enc_proj ----------------
__global__ __launch_bounds__(256) void fatpre_k(const int* __restrict__ edges,
                                                int* __restrict__ deg, int E, int nE,
                                                const float* __restrict__ g0w0,
                                                const float* __restrict__ g0w1,
                                                const float* __restrict__ gw0,
                                                const float* __restrict__ gw1,
                                                unsigned short* __restrict__ Wt,
                                                const float* __restrict__ bw,
                                                unsigned short* __restrict__ bwT,
                                                const float* __restrict__ enc,
                                                float* __restrict__ encp, int B_) {
    int bid = blockIdx.x;
    int tid = threadIdx.x;
    if (bid < nE) {
        int e = bid * 256 + tid;
        if (e < E) {
            atomicAdd(&deg[edges[2 * e]], 1);
            atomicAdd(&deg[edges[2 * e + 1]], 1);
        }
    } else if (bid < nE + 16) {
        int lh = bid - nE;
        int l = lh >> 1, h = lh & 1;
        const float* src;
        if (l == 0) src = h ? g0w1 : g0w0;
        else src = (h ? gw1 : gw0) + (size_t)(l - 1) * 16384;
        unsigned short* dst = Wt + (size_t)lh * 16384;
        for (int idx = tid; idx < 16384; idx += 256) {
            int n = idx >> 7, k = idx & 127;
            dst[n * 128 + k] = f2bf(src[k * 128 + n]);
        }
    } else if (bid < nE + 46) {
        // bottleneck weight transpose+cast: bwT[n][k] = bf16(bw[k][n])
        int blk = bid - nE - 16;  // 0..29
        for (int idx = tid; idx < 16384; idx += 256) {
            int n = idx >> 7, kk = idx & 127;
            bwT[(size_t)n * 3840 + blk * 128 + kk] =
                f2bf(bw[(size_t)(blk * 128 + kk) * 128 + n]);
        }
    } else {
        int b = bid - nE - 46;
        int sH = tid >> 7;
        int j = tid & 127;
        const float* w = sH ? g0w1 : g0w0;
        const float* eb = enc + b * 256;
        float acc = 0.f;
        for (int c = 0; c < 256; ++c) acc = fmaf(eb[c], w[(131 + c) * 128 + j], acc);
        encp[(sH * B_ + b) * 128 + j] = acc;
    }
}

// ---------------- pixel projection via MFMA (K=128/block, LDS-staged coalesced A) -----
// A-tile staged through LDS: float4 reads along HW (fully coalesced, 4 loads/
// thread/chunk vs 16 scalars) into tl[64][65], then K-contiguous fragment
// reads from LDS (conflict-free; same pattern as fatpre's transpose role).
__global__ __launch_bounds__(256) void proj_all_k(
    const float* __restrict__ fm1, const float* __restrict__ fm2,
    const float* __restrict__ fm3, const float* __restrict__ fm4,
    const unsigned short* __restrict__ bwT, float* __restrict__ o1, float* __restrict__ o2,
    float* __restrict__ o3, float* __restrict__ o4, int B_) {
    __shared__ unsigned short wlds[8192];  // 16 KB: [128 n][64 k] bf16, XOR-swizzled
    __shared__ float tl[64][65];           // 16.6 KB: [k][p] fp32 A staging

    int tid = threadIdx.x;
    int n1 = 49 * B_ * 2, n2 = 13 * B_ * 4, n3 = 4 * B_ * 8;
    int bid = blockIdx.x;
    const float* fm;
    float* op;
    int C, HW, PT, idx, koff;
    if (bid < n1) {
        fm = fm1; op = o1; C = 256; HW = 3136; PT = 49; idx = bid; koff = 0;
    } else if (bid < n1 + n2) {
        fm = fm2; op = o2; C = 512; HW = 784; PT = 13; idx = bid - n1; koff = 256;
    } else if (bid < n1 + n2 + n3) {
        fm = fm3; op = o3; C = 1024; HW = 196; PT = 4; idx = bid - n1 - n2; koff = 768;
    } else {
        fm = fm4; op = o4; C = 2048; HW = 49; PT = 1; idx = bid - n1 - n2 - n3; koff = 1792;
    }
    int pt = idx % PT;
    int r2 = idx / PT;
    int b = r2 % B_;
    int zz = r2 / B_;
    int p0 = pt * 64;
    const float* fmb = fm + (size_t)b * C * HW;
    int kcf0 = zz * 128;  // this block's 128-wide channel window

    int wave = tid >> 6, lane = tid & 63;
    int row16 = lane & 15, quad = lane >> 4;
    int pl = wave * 16 + row16;  // local pixel 0..63 for A-fragment

    floatx4 acc[8];
#pragma unroll
    for (int j = 0; j < 8; ++j) acc[j] = (floatx4){0.f, 0.f, 0.f, 0.f};

#pragma unroll
    for (int zz2 = 0; zz2 < 2; ++zz2) {
        int kcf = kcf0 + zz2 * 64;
        int kcw = koff + kcf;
        if (zz2) __syncthreads();  // protect previous chunk's wlds/tl reads
        // stage W^T tile [128 n][64 k] bf16, swizzled
#pragma unroll
        for (int l = 0; l < 4; ++l) {
            int i2 = tid + l * 256;  // 0..1023
            int n = i2 >> 3, c16 = i2 & 7;
            *(short8*)&wlds[n * 64 + ((c16 ^ (n & 7)) * 8)] =
                *(const short8*)(bwT + (size_t)n * 3840 + kcw + c16 * 8);
        }
        // stage A tile [64 k][64 p] fp32: float4 along HW (coalesced)
#pragma unroll
        for (int l = 0; l < 4; ++l) {
            int i2 = tid + l * 256;  // 0..1023
            int ch = i2 >> 4;
            int pq = (i2 & 15) * 4;
            const float* src = fmb + (size_t)(kcf + ch) * HW + p0 + pq;
            float4 v;
            if (p0 + pq + 3 < HW) {
                v = *(const float4*)src;
            } else {
                v.x = (p0 + pq + 0 < HW) ? src[0] : 0.f;
                v.y = (p0 + pq + 1 < HW) ? src[1] : 0.f;
                v.z = (p0 + pq + 2 < HW) ? src[2] : 0.f;
                v.w = (p0 + pq + 3 < HW) ? src[3] : 0.f;
            }
            tl[ch][pq + 0] = v.x;
            tl[ch][pq + 1] = v.y;
            tl[ch][pq + 2] = v.z;
            tl[ch][pq + 3] = v.w;
        }
        __syncthreads();
        // A-fragments from LDS (K-contiguous scalars; lanes read distinct p -> no conflict)
        short8 ax[2];
#pragma unroll
        for (int ks = 0; ks < 2; ++ks) {
#pragma unroll
            for (int j = 0; j < 8; ++j)
                ax[ks][j] = (short)f2bf(tl[ks * 32 + quad * 8 + j][pl]);
        }
#pragma unroll
        for (int ks = 0; ks < 2; ++ks) {
            int c = ks * 4 + quad;
#pragma unroll
            for (int nt = 0; nt < 8; ++nt) {
                int wr = nt * 16 + row16;
                short8 bwf = *(short8*)&wlds[wr * 64 + ((c ^ (wr & 7)) * 8)];
                acc[nt] =
                    __builtin_amdgcn_mfma_f32_16x16x32_bf16(ax[ks], bwf, acc[nt], 0, 0, 0);
            }
        }
    }

    float* obase = op + (size_t)b * HW * 128;
#pragma unroll
    for (int nt = 0; nt < 8; ++nt) {
        int colg = nt * 16 + row16;
#pragma unroll
        for (int rr = 0; rr < 4; ++rr) {
            int pr = p0 + wave * 16 + quad * 4 + rr;
            if (pr < HW) atomicAdd(&obase[(size_t)pr * 128 + colg], acc[nt][rr]);
        }
    }
}

// ---------------- bilinear sample + bottleneck relu + layer0 pre terms ----------------
__device__ __forceinline__ float sample_level(const float* __restrict__ pp, int Hh, int Ww,
                                              float gx, float gy, int j) {
    float x = (gx + 1.f) * 0.5f * (float)(Ww - 1);
    float y = (gy + 1.f) * 0.5f * (float)(Hh - 1);
    float x0f = floorf(x), y0f = floorf(y);
    float wx1 = x - x0f, wy1 = y - y0f;
    float wx0 = 1.f - wx1, wy0 = 1.f - wy1;
    int x0 = (int)fminf(fmaxf(x0f, 0.f), (float)(Ww - 1));
    int x1 = (int)fminf(fmaxf(x0f + 1.f, 0.f), (float)(Ww - 1));
    int y0 = (int)fminf(fmaxf(y0f, 0.f), (float)(Hh - 1));
    int y1 = (int)fminf(fmaxf(y0f + 1.f, 0.f), (float)(Hh - 1));
    const float* r00 = pp + (size_t)(y0 * Ww + x0) * 128;
    const float* r01 = pp + (size_t)(y0 * Ww + x1) * 128;
    const float* r10 = pp + (size_t)(y1 * Ww + x0) * 128;
    const float* r11 = pp + (size_t)(y1 * Ww + x1) * 128;
    return wy0 * (wx0 * r00[j] + wx1 * r01[j]) + wy1 * (wx0 * r10[j] + wx1 * r11[j]);
}

__global__ __launch_bounds__(128) void sample_bottleneck_k(
    const float* __restrict__ av, const float* __restrict__ pp1, const float* __restrict__ pp2,
    const float* __restrict__ pp3, const float* __restrict__ pp4, const float* __restrict__ bb,
    const float* __restrict__ verts, const float* __restrict__ encp,
    const float* __restrict__ g0w0, const float* __restrict__ g0w1,
    const float* __restrict__ g0b0, const float* __restrict__ g0b1,
    unsigned short* __restrict__ X, unsigned short* __restrict__ H, int V_, int B_) {
    int n = blockIdx.x, j = threadIdx.x;
    int b = n / V_;
    float gx = av[(size_t)n * 3 + 0];
    float gy = av[(size_t)n * 3 + 1];
    float acc = bb[j];
    acc += sample_level(pp1 + (size_t)b * 3136 * 128, 56, 56, gx, gy, j);
    acc += sample_level(pp2 + (size_t)b * 784 * 128, 28, 28, gx, gy, j);
    acc += sample_level(pp3 + (size_t)b * 196 * 128, 14, 14, gx, gy, j);
    acc += sample_level(pp4 + (size_t)b * 49 * 128, 7, 7, gx, gy, j);
    X[(size_t)n * 128 + j] = f2bf(fmaxf(acc, 0.f));
    float v0 = verts[n * 3 + 0], v1 = verts[n * 3 + 1], v2 = verts[n * 3 + 2];
    float h0 = encp[(0 * B_ + b) * 128 + j] + g0b0[j] + v0 * g0w0[128 * 128 + j] +
               v1 * g0w0[129 * 128 + j] + v2 * g0w0[130 * 128 + j];
    float h1 = encp[(1 * B_ + b) * 128 + j] + g0b1[j] + v0 * g0w1[128 * 128 + j] +
               v1 * g0w1[129 * 128 + j] + v2 * g0w1[130 * 128 + j];
    H[(size_t)n * 256 + j] = f2bf(h0);
    H[(size_t)n * 256 + 128 + j] = f2bf(h1);
}

// ---------------- layer-0 gather v2: 4 vertices/wave, AggX=sum X, AggH=h0+sum h1 -------
__global__ __launch_bounds__(256) void agg0_k(const unsigned short* __restrict__ X,
                                              const unsigned short* __restrict__ H,
                                              const int* __restrict__ rowptr,
                                              const int* __restrict__ adj,
                                              unsigned short* __restrict__ AggX,
                                              unsigned short* __restrict__ AggH, int Nv,
                                              int Etot) {
    int wave = threadIdx.x >> 6, lane = threadIdx.x & 63;
    int n0 = (blockIdx.x * 4 + wave) * 4;
    if (n0 >= Nv) return;
    int g = lane >> 4, c = lane & 15;
    int rp = rowptr[min(n0 + (lane & 7), Nv)];
    int sg = __shfl(rp, g);
    int eg = __shfl(rp, g + 1);
    int m = eg - sg;
    m = max(m, __shfl_xor(m, 16));
    m = max(m, __shfl_xor(m, 32));

    int n = n0 + g;
    bool nok = (n < Nv);
    int nc = nok ? n : (Nv - 1);
    float accx[8], acch[8];
    short8 h0v = *(const short8*)(H + (size_t)nc * 256 + c * 8);
#pragma unroll
    for (int j = 0; j < 8; ++j) {
        accx[j] = 0.f;
        acch[j] = bf2f((unsigned short)h0v[j]);
    }

    for (int it = 0; it < m; it += 8) {
        int t = sg + it + (lane & 7);
        int adjv = adj[min(t, Etot - 1)];
        short8 bx[8], bh[8];
#pragma unroll
        for (int q = 0; q < 8; ++q) {
            int nbq = __shfl(adjv, (lane & 48) + q);
            bx[q] = *(const short8*)(X + (size_t)nbq * 128 + c * 8);
            bh[q] = *(const short8*)(H + (size_t)nbq * 256 + 128 + c * 8);
        }
#pragma unroll
        for (int q = 0; q < 8; ++q) {
            bool ok = (sg + it + q < eg);
#pragma unroll
            for (int j = 0; j < 8; ++j) {
                accx[j] += ok ? bf2f((unsigned short)bx[q][j]) : 0.f;
                acch[j] += ok ? bf2f((unsigned short)bh[q][j]) : 0.f;
            }
        }
    }
    if (nok) {
        short8 ox, oh;
#pragma unroll
        for (int j = 0; j < 8; ++j) {
            ox[j] = (short)f2bf(accx[j]);
            oh[j] = (short)f2bf(acch[j]);
        }
        *(short8*)(AggX + (size_t)n * 128 + c * 8) = ox;
        *(short8*)(AggH + (size_t)n * 128 + c * 8) = oh;
    }
}

// ---------------- gather v2: 4 vertices/wave, 16-lane groups, short8 lane loads ----------
__global__ __launch_bounds__(256) void agg_x_k(const unsigned short* __restrict__ X,
                                               const int* __restrict__ rowptr,
                                               const int* __restrict__ adj,
                                               unsigned short* __restrict__ Agg, int Nv,
                                               int Etot) {
    int wave = threadIdx.x >> 6, lane = threadIdx.x & 63;
    int n0 = (blockIdx.x * 4 + wave) * 4;
    if (n0 >= Nv) return;
    int g = lane >> 4, c = lane & 15;
    int rp = rowptr[min(n0 + (lane & 7), Nv)];  // lanes 0..4 meaningful
    int sg = __shfl(rp, g);
    int eg = __shfl(rp, g + 1);
    int m = eg - sg;
    m = max(m, __shfl_xor(m, 16));
    m = max(m, __shfl_xor(m, 32));  // max degree over the 4 groups

    float acc[8];
#pragma unroll
    for (int j = 0; j < 8; ++j) acc[j] = 0.f;

    for (int it = 0; it < m; it += 8) {
        int t = sg + it + (lane & 7);
        int adjv = adj[min(t, Etot - 1)];
        short8 buf[8];
#pragma unroll
        for (int q = 0; q < 8; ++q) {
            int nbq = __shfl(adjv, (lane & 48) + q);  // group base lane + q
            buf[q] = *(const short8*)(X + (size_t)nbq * 128 + c * 8);
        }
#pragma unroll
        for (int q = 0; q < 8; ++q) {
            bool ok = (sg + it + q < eg);
#pragma unroll
            for (int j = 0; j < 8; ++j) {
                float v = bf2f((unsigned short)buf[q][j]);
                acc[j] += ok ? v : 0.f;
            }
        }
    }

    if (n0 + g < Nv) {
        short8 o;
#pragma unroll
        for (int j = 0; j < 8; ++j) o[j] = (short)f2bf(acc[j]);
        *(short8*)(Agg + (size_t)(n0 + g) * 128 + c * 8) = o;
    }
}

// ---------------- dual-MFMA layer GEMM: 128-row x 64-col tiles ----------------
// Layer 0: aggh (h0 + gathered h1 sums) supplies the affine terms.
// Last layer: head fused -- out[gm] += sum_col relu(x)[gm,col] * off_w[col,:].
__global__ __launch_bounds__(256, 3) void gemm_dual_k(
    const unsigned short* __restrict__ Xin, const unsigned short* __restrict__ Agg,
    const unsigned short* __restrict__ Wt,  // [2][128][128] bf16 n-major (W0, W1)
    const float* __restrict__ b0, const float* __restrict__ b1,
    const unsigned short* __restrict__ aggh, const int* __restrict__ degv,
    unsigned short* __restrict__ Xout, int M, const float* __restrict__ ow,
    const float* __restrict__ ob, float* __restrict__ outp) {
    __shared__ unsigned short wlds[16384];  // 32 KB weights (stays live both sub-tiles)
    __shared__ unsigned short cs[64 * 72];  // 9 KB epilogue staging
    __shared__ float bS[128];
    __shared__ float owS[192];  // head weights for this yb half

    int tid = threadIdx.x;
    int m0 = blockIdx.x * 128;
    int yb = blockIdx.y;

    int wave = tid >> 6, lane = tid & 63;
    int row16 = lane & 15;
    int quad = lane >> 4;
    int wrow = wave * 16;

    // prefetch A + deg for sub-tile 0 (overlaps weight staging)
    short8 axT[2][4], agT[2][4];
    int dgT[2][4];
    {
        int g = min(m0 + wrow + row16, M - 1);
#pragma unroll
        for (int ks = 0; ks < 4; ++ks) {
            int koff = ks * 32 + quad * 8;
            axT[0][ks] = *(const short8*)(Xin + (size_t)g * 128 + koff);
            agT[0][ks] = *(const short8*)(Agg + (size_t)g * 128 + koff);
        }
#pragma unroll
        for (int rr = 0; rr < 4; ++rr)
            dgT[0][rr] = degv[min(m0 + wrow + quad * 4 + rr, M - 1)];
    }

    if (tid < 64) {
        bS[tid] = b0 ? b0[yb * 64 + tid] : 0.f;
        bS[64 + tid] = b1 ? b1[yb * 64 + tid] : 0.f;
    }
    if (outp && tid < 192) owS[tid] = ow[yb * 192 + tid];

    const unsigned short* W0h = Wt + (size_t)yb * 64 * 128;
    const unsigned short* W1h = Wt + 16384 + (size_t)yb * 64 * 128;
#pragma unroll
    for (int l = 0; l < 8; ++l) {
        int idx = tid + l * 256;      // 0..2047 16B chunks
        int half = idx >> 10;
        int r = (idx >> 4) & 63;
        int c16 = idx & 15;
        int sw = (c16 ^ (r & 15)) * 8;
        const unsigned short* src = (half ? W1h : W0h) + r * 128 + c16 * 8;
        *(short8*)&wlds[half * 8192 + r * 128 + sw] = *(const short8*)src;
    }
    __syncthreads();

    // prefetch A + deg for sub-tile 1 (overlaps sub-tile-0 MFMA)
    {
        int g = min(m0 + 64 + wrow + row16, M - 1);
#pragma unroll
        for (int ks = 0; ks < 4; ++ks) {
            int koff = ks * 32 + quad * 8;
            axT[1][ks] = *(const short8*)(Xin + (size_t)g * 128 + koff);
            agT[1][ks] = *(const short8*)(Agg + (size_t)g * 128 + koff);
        }
#pragma unroll
        for (int rr = 0; rr < 4; ++rr)
            dgT[1][rr] = degv[min(m0 + 64 + wrow + quad * 4 + rr, M - 1)];
    }

#pragma unroll
    for (int t = 0; t < 2; ++t) {
        int mT = m0 + t * 64;
        floatx4 acc[4];
#pragma unroll
        for (int j = 0; j < 4; j++) acc[j] = (floatx4){0.f, 0.f, 0.f, 0.f};

#pragma unroll
        for (int ks = 0; ks < 4; ++ks) {
            int c = ks * 4 + quad;
#pragma unroll
            for (int nt = 0; nt < 4; ++nt) {
                int wr = nt * 16 + row16;
                short8 bw0 = *(short8*)&wlds[wr * 128 + ((c ^ row16) * 8)];
                short8 bw1 = *(short8*)&wlds[8192 + wr * 128 + ((c ^ row16) * 8)];
                acc[nt] = __builtin_amdgcn_mfma_f32_16x16x32_bf16(axT[t][ks], bw0, acc[nt], 0, 0, 0);
                acc[nt] = __builtin_amdgcn_mfma_f32_16x16x32_bf16(agT[t][ks], bw1, acc[nt], 0, 0, 0);
            }
        }

        // epilogue -> cs (each wave writes its own 16 rows)
        unsigned short cvs[4][4];
#pragma unroll
        for (int nt = 0; nt < 4; ++nt) {
            int colh = nt * 16 + row16;
            int colg = yb * 64 + colh;
            float bc0 = bS[colh];
            float bc1 = bS[64 + colh];
#pragma unroll
            for (int rr = 0; rr < 4; ++rr) {
                int row = wrow + quad * 4 + rr;
                int gm = mT + row;
                float v = acc[nt][rr] + bc0 + (float)dgT[t][rr] * bc1;
                if (aggh && gm < M) v += bf2f(aggh[(size_t)gm * 128 + colg]);
                unsigned short cv = f2bf(fmaxf(v, 0.f));
                cvs[nt][rr] = cv;
                cs[row * 72 + colh] = cv;
            }
        }

        // fused head (last layer only): per-row 3-dot over this yb half
        if (outp) {
#pragma unroll
            for (int rr = 0; rr < 4; ++rr) {
                float h0 = 0.f, h1 = 0.f, h2 = 0.f;
#pragma unroll
                for (int nt = 0; nt < 4; ++nt) {
                    int colh = nt * 16 + row16;
                    float xv = bf2f(cvs[nt][rr]);
                    h0 += xv * owS[colh * 3 + 0];
                    h1 += xv * owS[colh * 3 + 1];
                    h2 += xv * owS[colh * 3 + 2];
                }
#pragma unroll
                for (int mm = 1; mm < 16; mm <<= 1) {
                    h0 += __shfl_xor(h0, mm);
                    h1 += __shfl_xor(h1, mm);
                    h2 += __shfl_xor(h2, mm);
                }
                if (row16 == 0) {
                    int gm = mT + wrow + quad * 4 + rr;
                    if (gm < M) {
                        float e0 = (yb == 0) ? ob[0] : 0.f;
                        float e1 = (yb == 0) ? ob[1] : 0.f;
                        float e2 = (yb == 0) ? ob[2] : 0.f;
                        atomicAdd(&outp[gm * 3 + 0], h0 + e0);
                        atomicAdd(&outp[gm * 3 + 1], h1 + e1);
                        atomicAdd(&outp[gm * 3 + 2], h2 + e2);
                    }
                }
            }
        }
        __syncthreads();

        // coalesced copy-out
        {
            int r = tid >> 2;
            int cq = (tid & 3) * 16;
            int gm = mT + r;
            if (gm < M) {
                unsigned short* dst = Xout + (size_t)gm * 128 + yb * 64 + cq;
                *(short8*)dst = *(short8*)&cs[r * 72 + cq];
                *(short8*)(dst + 8) = *(short8*)&cs[r * 72 + cq + 8];
            }
        }
        __syncthreads();  // cs reads done before next sub-tile overwrites
    }
}

extern "C" void kernel_launch(void* const* d_in, const int* in_sizes, int n_in, void* d_out,
                              int out_size, void* d_ws, size_t ws_size, hipStream_t stream) {
    const float* feat1 = (const float*)d_in[0];
    const float* feat2 = (const float*)d_in[1];
    const float* feat3 = (const float*)d_in[2];
    const float* feat4 = (const float*)d_in[3];
    const float* av = (const float*)d_in[4];
    const float* verts = (const float*)d_in[5];
    const float* image_enc = (const float*)d_in[6];
    const int* edges = (const int*)d_in[7];
    const float* bw = (const float*)d_in[8];
    const float* bb = (const float*)d_in[9];
    const float* g0w0 = (const float*)d_in[10];
    const float* g0b0 = (const float*)d_in[11];
    const float* g0w1 = (const float*)d_in[12];
    const float* g0b1 = (const float*)d_in[13];
    const float* gw0 = (const float*)d_in[14];
    const float* gb0 = (const float*)d_in[15];
    const float* gw1 = (const float*)d_in[16];
    const float* gb1 = (const float*)d_in[17];
    const float* off_w = (const float*)d_in[18];
    const float* off_b = (const float*)d_in[19];

    int B_ = in_sizes[6] / 256;  // 4
    int N_ = in_sizes[5] / 3;    // 40968
    int V_ = N_ / B_;            // 10242
    int E_ = in_sizes[7] / 2;    // 122880

    char* wsb = (char*)d_ws;
    size_t off = 0;
    auto alloc = [&](size_t bytes) -> void* {
        void* p = (void*)(wsb + off);
        off += (bytes + 255) & ~(size_t)255;
        return p;
    };
    int S1 = B_ * 3136 * 128;
    int S2 = B_ * 784 * 128;
    int S3 = B_ * 196 * 128;
    int S4 = B_ * 49 * 128;
    float* pp1 = (float*)alloc((size_t)S1 * 4);
    float* pp2 = (float*)alloc((size_t)S2 * 4);
    float* pp3 = (float*)alloc((size_t)S3 * 4);
    float* pp4 = (float*)alloc((size_t)S4 * 4);
    size_t pp_bytes = off;  // contiguous pp region starts at wsb
    unsigned short* XA = (unsigned short*)alloc((size_t)N_ * 128 * 2);
    unsigned short* XB = (unsigned short*)alloc((size_t)N_ * 128 * 2);
    unsigned short* AggB = (unsigned short*)alloc((size_t)N_ * 128 * 2);
    unsigned short* AggH = (unsigned short*)alloc((size_t)N_ * 128 * 2);
    unsigned short* Hb = (unsigned short*)alloc((size_t)N_ * 256 * 2);
    unsigned short* Wt = (unsigned short*)alloc((size_t)8 * 2 * 128 * 128 * 2);
    unsigned short* bwT = (unsigned short*)alloc((size_t)128 * 3840 * 2);
    float* encp = (float*)alloc((size_t)2 * B_ * 128 * 4);
    int* deg = (int*)alloc((size_t)(N_ + 1) * 4);
    int* rowptr = (int*)alloc((size_t)(N_ + 1) * 4);
    int* cursor = (int*)alloc((size_t)N_ * 4);
    int* excl = (int*)alloc((size_t)N_ * 4);
    int* bsum = (int*)alloc((size_t)64 * 4);
    int* adj = (int*)alloc((size_t)2 * E_ * 4);

    hipMemsetAsync(deg, 0, (N_ + 1) * sizeof(int), stream);
    hipMemsetAsync(wsb, 0, pp_bytes, stream);    // zero pp for atomic accumulation
    hipMemsetAsync(d_out, 0, out_size, stream);  // zero out for fused-head atomics

    // fat prologue: count_deg | prep_w | prep_bwT | enc_proj
    int nE = ceil_div(E_, 256);
    fatpre_k<<<nE + 46 + B_, 256, 0, stream>>>(edges, deg, E_, nE, g0w0, g0w1, gw0, gw1, Wt,
                                               bw, bwT, image_enc, encp, B_);

    // CSR scan + fill
    int nb = ceil_div(N_, 1024);
    scan1_k<<<nb, 1024, 0, stream>>>(deg, excl, bsum, N_);
    scan3_k<<<nb, 1024, 0, stream>>>(excl, bsum, deg, rowptr, cursor, N_, nb);
    fill_adj_k<<<ceil_div(E_, 256), 256, 0, stream>>>(edges, cursor, adj, E_);

    // pixel projection via MFMA (K=128 per block, LDS-staged A, atomic into pp)
    int nproj = 49 * B_ * 2 + 13 * B_ * 4 + 4 * B_ * 8 + 1 * B_ * 16;
    proj_all_k<<<nproj, 256, 0, stream>>>(feat1, feat2, feat3, feat4, bwT, pp1, pp2, pp3, pp4,
                                          B_);

    // sample + bottleneck -> XA (bf16 X0); layer0 pre terms (biases baked) -> Hb (bf16)
    sample_bottleneck_k<<<N_, 128, 0, stream>>>(av, pp1, pp2, pp3, pp4, bb, verts, encp, g0w0,
                                                g0w1, g0b0, g0b1, XA, Hb, V_, B_);

    dim3 ggrid(ceil_div(N_, 128), 2);
    int agrid4 = ceil_div(N_, 16);
    // layer 0: one v2 adj walk gathers X-sums AND (h0 + h1-sums); epilogue adds AggH
    agg0_k<<<agrid4, 256, 0, stream>>>(XA, Hb, rowptr, adj, AggB, AggH, N_, 2 * E_);
    gemm_dual_k<<<ggrid, 256, 0, stream>>>(XA, AggB, Wt, nullptr, nullptr, AggH, deg, XB, N_,
                                           nullptr, nullptr, nullptr);
    unsigned short* Xc = XB;
    unsigned short* Xn = XA;
    for (int i = 0; i < 7; ++i) {
        bool last = (i == 6);
        agg_x_k<<<agrid4, 256, 0, stream>>>(Xc, rowptr, adj, AggB, N_, 2 * E_);
        gemm_dual_k<<<ggrid, 256, 0, stream>>>(Xc, AggB, Wt + (size_t)(i + 1) * 32768,
                                               gb0 + i * 128, gb1 + i * 128, nullptr, deg, Xn,
                                               N_, last ? off_w : nullptr,
                                               last ? off_b : nullptr,
                                               last ? (float*)d_out : nullptr);
        unsigned short* t = Xc;
        Xc = Xn;
        Xn = t;
    }
}